// Round 1
// baseline (858.893 us; speedup 1.0000x reference)
//
#include <hip/hip_runtime.h>
#include <cmath>

typedef unsigned short u16;
typedef unsigned int u32;
typedef __attribute__((ext_vector_type(8))) short short8;
typedef __attribute__((ext_vector_type(4))) float f32x4;

#define B_    64
#define NV    385
#define CDIM  768
#define NQ    321
#define SFL   256
#define NH    12
#define HD    64
#define MQ    (B_*NV)   /* 24640 */
#define MP    (B_*NQ)   /* 20544 */
#define MD    (B_*SFL)  /* 16384 */
#define SCALE_ 0.125f
#define EPS_   1e-6f

__device__ __forceinline__ u16 f2b(float f) {
  u32 x = __float_as_uint(f);
  return (u16)((x + 0x7FFFu + ((x >> 16) & 1u)) >> 16);
}

__device__ __forceinline__ void gload_lds16(const void* g, void* l) {
  __builtin_amdgcn_global_load_lds(
      (const __attribute__((address_space(1))) u32*)g,
      (__attribute__((address_space(3))) u32*)l,
      16, 0, 0);
}

// ---------------- fp32 -> bf16 convert (vectorized) ----------------
__global__ void k_convert4(const float4* __restrict__ in, ushort4* __restrict__ out, int n4) {
  int i = blockIdx.x * blockDim.x + threadIdx.x;
  if (i < n4) {
    float4 v = in[i];
    ushort4 o;
    o.x = f2b(v.x); o.y = f2b(v.y); o.z = f2b(v.z); o.w = f2b(v.w);
    out[i] = o;
  }
}

// ---------------- tgt_rep = mean over x[:, 65:129, :] ----------------
__global__ void k_tgt(const float* __restrict__ x, float* __restrict__ tgt) {
  int b = blockIdx.x, c = threadIdx.x; // block = 768 threads
  float s = 0.f;
  for (int j = 0; j < 64; ++j) s += x[((size_t)(b*NV + 65 + j))*CDIM + c];
  tgt[b*CDIM + c] = s * (1.f/64.f);
}

// ---------------- 128x128 bf16 MFMA GEMM, BK=64, XOR-swizzled LDS ----------------
__global__ __launch_bounds__(256) void k_gemm128(const u16* __restrict__ A, const u16* __restrict__ W,
                                                 const float* __restrict__ bias,
                                                 u16* __restrict__ Cb, float* __restrict__ Cf,
                                                 int M, int N, int K, int mode) {
  __shared__ __align__(16) u16 sbuf[128*128];  // 32 KB: As=sbuf[0:8192), Ws=sbuf[8192:16384)
  u16* As = sbuf;
  u16* Ws = sbuf + 8192;
  int tid = threadIdx.x;
  int wave = tid >> 6, lane = tid & 63;
  int quad = lane >> 4, col = lane & 15;
  int m0 = blockIdx.y * 128, n0 = blockIdx.x * 128;

  const u16* pa[4];
  const u16* pb[4];
#pragma unroll
  for (int p = 0; p < 4; ++p) {
    int c = p*256 + tid;
    int row = c >> 3;
    int sg = (c & 7) ^ (row & 7);          // XOR swizzle (source-side)
    pa[p] = A + (size_t)min(m0 + row, M - 1) * K + sg*8;
    pb[p] = W + (size_t)(n0 + row) * K + sg*8;
  }

  int wm = (wave >> 1) * 64, wn = (wave & 1) * 64;
  f32x4 acc[4][4];
  f32x4 z4 = {0.f, 0.f, 0.f, 0.f};
#pragma unroll
  for (int i = 0; i < 4; ++i)
#pragma unroll
    for (int j = 0; j < 4; ++j) acc[i][j] = z4;

  for (int k0 = 0; k0 < K; k0 += 64) {
#pragma unroll
    for (int p = 0; p < 4; ++p) {
      gload_lds16(pa[p], &As[(p*256 + wave*64) * 8]);
      gload_lds16(pb[p], &Ws[(p*256 + wave*64) * 8]);
      pa[p] += 64; pb[p] += 64;
    }
    __syncthreads();

#pragma unroll
    for (int kk = 0; kk < 2; ++kk) {
      int sr = quad + kk*4;                // 16B chunk index within the 64-u16 row
      short8 af[4], bf[4];
#pragma unroll
      for (int i = 0; i < 4; ++i) {
        int row = wm + i*16 + col;
        af[i] = *(const short8*)&As[row*64 + ((sr ^ (row & 7)) * 8)];
      }
#pragma unroll
      for (int j = 0; j < 4; ++j) {
        int row = wn + j*16 + col;
        bf[j] = *(const short8*)&Ws[row*64 + ((sr ^ (row & 7)) * 8)];
      }
#pragma unroll
      for (int i = 0; i < 4; ++i)
#pragma unroll
        for (int j = 0; j < 4; ++j)
          acc[i][j] = __builtin_amdgcn_mfma_f32_16x16x32_bf16(af[i], bf[j], acc[i][j], 0, 0, 0);
    }
    __syncthreads();
  }

  if (mode == 0) {
#pragma unroll
    for (int j = 0; j < 4; ++j) {
      int cc = wn + j*16 + col;
      float bv = bias ? bias[n0 + cc] : 0.f;
#pragma unroll
      for (int i = 0; i < 4; ++i)
#pragma unroll
        for (int ii = 0; ii < 4; ++ii) {
          int row = wm + i*16 + quad*4 + ii;
          sbuf[row*128 + cc] = f2b(acc[i][j][ii] + bv);
        }
    }
    __syncthreads();
#pragma unroll
    for (int q = 0; q < 8; ++q) {
      int idx = q*256 + tid;
      int row = idx >> 4, c16 = idx & 15;
      if (m0 + row < M)
        *(float4*)(Cb + (size_t)(m0 + row) * N + n0 + c16*8) = *(const float4*)&sbuf[row*128 + c16*8];
    }
  } else {
#pragma unroll
    for (int j = 0; j < 4; ++j) {
      int cc = n0 + wn + j*16 + col;
      float bv = bias ? bias[cc] : 0.f;
#pragma unroll
      for (int i = 0; i < 4; ++i) {
        int r = m0 + wm + i*16 + quad*4;
#pragma unroll
        for (int ii = 0; ii < 4; ++ii) {
          if (r + ii < M) Cf[(size_t)(r + ii) * N + cc] = acc[i][j][ii] + bv;
        }
      }
    }
  }
}

// ---------------- fp32 GEMM v2 (decision path stays fp32) ----------------
__device__ __forceinline__ float gelu_exact(float x) {
  return 0.5f * x * (1.f + erff(x * 0.70710678118654752f));
}
__global__ __launch_bounds__(256) void k_gemm_f32(const float* __restrict__ A,
                                                  const float* __restrict__ x,
                                                  const float* __restrict__ W, int ldw,
                                                  const float* __restrict__ bias,
                                                  float* __restrict__ C, int M, int N, int K,
                                                  int gather, int gelu, int bias2d) {
  __shared__ __align__(16) float As[16][132];
  __shared__ __align__(16) float Ws[16][68];
  int tid = threadIdx.x;
  int tx = tid & 15, ty = tid >> 4;
  int n0 = blockIdx.x * 64, m0 = blockIdx.y * 128;
  float acc[8][4] = {};

  for (int k0 = 0; k0 < K; k0 += 16) {
#pragma unroll
    for (int p = 0; p < 2; ++p) {
      int f = p * 256 + tid;
      int row = f >> 2, kc = (f & 3) * 4;
      float4 v;
      if (gather) {
        int m = m0 + row;
        int b = m >> 8, s2 = m & 255;
        v = *(const float4*)(x + ((size_t)(b*NV + 129 + s2))*CDIM + k0 + kc);
      } else {
        int m = min(m0 + row, M - 1);
        v = *(const float4*)(A + (size_t)m * K + k0 + kc);
      }
      As[kc+0][row] = v.x; As[kc+1][row] = v.y; As[kc+2][row] = v.z; As[kc+3][row] = v.w;
    }
    {
      int row = tid >> 2, kc = (tid & 3) * 4;
      float4 wv = *(const float4*)(W + (size_t)(n0 + row) * ldw + k0 + kc);
      Ws[kc+0][row] = wv.x; Ws[kc+1][row] = wv.y; Ws[kc+2][row] = wv.z; Ws[kc+3][row] = wv.w;
    }
    __syncthreads();
#pragma unroll
    for (int k2 = 0; k2 < 16; ++k2) {
      float4 a0 = *(const float4*)&As[k2][ty*8];
      float4 a1 = *(const float4*)&As[k2][ty*8 + 4];
      float4 wv = *(const float4*)&Ws[k2][tx*4];
      float a_[8] = {a0.x, a0.y, a0.z, a0.w, a1.x, a1.y, a1.z, a1.w};
      float w_[4] = {wv.x, wv.y, wv.z, wv.w};
#pragma unroll
      for (int i = 0; i < 8; ++i)
#pragma unroll
        for (int j = 0; j < 4; ++j) acc[i][j] += a_[i] * w_[j];
    }
    __syncthreads();
  }
#pragma unroll
  for (int i = 0; i < 8; ++i) {
    int r = m0 + ty*8 + i;
    if (r < M) {
      float4 o;
      float* op = (float*)&o;
#pragma unroll
      for (int j = 0; j < 4; ++j) {
        int n = n0 + tx*4 + j;
        float bv = bias2d ? bias[(size_t)(r >> 8) * N + n] : bias[n];
        float v = acc[i][j] + bv;
        op[j] = gelu ? gelu_exact(v) : v;
      }
      *(float4*)(C + (size_t)r * N + n0 + tx*4) = o;
    }
  }
}

// ---------------- decision: argmax of (h2 @ dp3_w.T + dp3_b), fp32 ----------------
__global__ void k_decision(const float* __restrict__ h2, const float* __restrict__ w3,
                           const float* __restrict__ b3, float* __restrict__ sdec) {
  int r = blockIdx.x * blockDim.x + threadIdx.x; // 16384 rows
  const float* hp = h2 + (size_t)r * 192;
  float l0 = b3[0], l1 = b3[1];
  for (int k = 0; k < 192; ++k) { float h = hp[k]; l0 += h * w3[k]; l1 += h * w3[192 + k]; }
  sdec[r] = (l1 > l0) ? 1.f : 0.f; // jnp.argmax ties -> 0
}

// ---------------- attention v2: 512 thr / 8 waves per (b,h); online softmax ----------------
// Changes vs v1: 8 waves (16 waves/CU at <=128 VGPR + 67.8KB LDS), online softmax over
// 64-key chunks (acc[25]->acc4[4], -84 VGPR), additive chunk-rotation swizzle on vsT
// (transpose writes conflict-free, PV reads provably uniform), eps/Nq folded into a
// precomputed vsum[d] term applied once in the epilogue.
__global__ __launch_bounds__(512, 4) void k_attn(const u16* __restrict__ qkvb, const float* __restrict__ sdec,
                                                 u16* __restrict__ O) {
  __shared__ __align__(16) u16 vsT[64*424];    // V^T swizzled: (d,n) at d*424 + cs*8 + (n&7)
  __shared__ __align__(16) u16 pst[8][16][40]; // per-wave P staging (16 rows x 32 keys, stride 40)
  __shared__ float sd[256];
  __shared__ float vpart[8][64];
  __shared__ float vsum[64];
  int b = blockIdx.x, h = blockIdx.y;
  int tid = threadIdx.x;
  int wave = tid >> 6, lane = tid & 63;
  int quad = lane >> 4, col = lane & 15;

  if (tid < 256) sd[tid] = sdec[b*SFL + tid];

  // zero-fill key range [385, 424) (chunks >= 48 are unswizzled)
  for (int i = tid; i < 64*39; i += 512) {
    int d = i / 39, n = 385 + (i - d*39);
    vsT[d*424 + n] = 0;
  }
  // transpose-stage V: thread (n, seg) -> 8 d-values; writes are bank-conflict-free:
  // bank = (j*20 + ((c+seg)&7)*4 + ni>>1) covers all 32 banks per j-step.
  for (int idx = tid; idx < NV*8; idx += 512) {
    int n = idx >> 3, seg = idx & 7;
    const u16* src = qkvb + ((size_t)(b*NV + n))*2304 + 1536 + h*HD + seg*8;
    int c = n >> 3;
#pragma unroll
    for (int j = 0; j < 8; ++j) {
      int d = seg*8 + j;
      int cs = (c < 48) ? ((c & ~7) | ((c + seg) & 7)) : c;
      vsT[d*424 + cs*8 + (n & 7)] = src[j];
    }
  }
  __syncthreads();

  // vsum[d] = sum over keys 0..384 of V[n][d] (for the eps/Nq term)
  {
    int d = tid & 63, part = tid >> 6;
    int n_lo = part*49, n_hi = min(n_lo + 49, 385);
    float s = 0.f;
    for (int n = n_lo; n < n_hi; ++n) {
      int c = n >> 3;
      int cs = (c < 48) ? ((c & ~7) | ((c + (d >> 3)) & 7)) : c;
      s += __uint_as_float((u32)vsT[d*424 + cs*8 + (n & 7)] << 16);
    }
    vpart[part][d] = s;
  }
  __syncthreads();
  if (tid < 64) {
    float s = 0.f;
#pragma unroll
    for (int p = 0; p < 8; ++p) s += vpart[p][tid];
    vsum[tid] = s;
  }
  __syncthreads();

  const u16* Qb = qkvb + ((size_t)(b*NV))*2304 + h*HD;
  const u16* Kb = Qb + 768;
  const f32x4 z4 = {0.f, 0.f, 0.f, 0.f};

  for (int t = wave; t < 21; t += 8) {
    int qn_a = t*16 + col;
    int pos = (qn_a == 0) ? 0 : (min(qn_a, 320) + 64);
    const u16* qp = Qb + (size_t)pos*2304 + quad*8;
    short8 aq0 = *(const short8*)(qp);
    short8 aq1 = *(const short8*)(qp + 32);

    float m_[4], l_[4];
    bool rowTpl[4], rowSearch[4];
    float sdq[4];
#pragma unroll
    for (int i = 0; i < 4; ++i) {
      m_[i] = -1e30f; l_[i] = 0.f;
      int qn = t*16 + quad*4 + i;
      rowTpl[i] = (qn >= 1 && qn <= 64);
      rowSearch[i] = (qn >= 65);
      sdq[i] = rowSearch[i] ? sd[min(qn - 65, 255)] : 1.f;
    }
    f32x4 oc[4];
#pragma unroll
    for (int nt = 0; nt < 4; ++nt) oc[nt] = z4;

    // 6 full chunks of 64 keys (0..383) — all keys valid, no guards needed
    for (int ch = 0; ch < 6; ++ch) {
      f32x4 acc4[4];
#pragma unroll
      for (int j = 0; j < 4; ++j) acc4[j] = z4;
#pragma unroll
      for (int j = 0; j < 4; ++j) {
        const u16* kp = Kb + (size_t)(ch*64 + j*16 + col)*2304;
        short8 b0 = *(const short8*)(kp + quad*8);
        short8 b1 = *(const short8*)(kp + 32 + quad*8);
        acc4[j] = __builtin_amdgcn_mfma_f32_16x16x32_bf16(aq0, b0, acc4[j], 0, 0, 0);
        acc4[j] = __builtin_amdgcn_mfma_f32_16x16x32_bf16(aq1, b1, acc4[j], 0, 0, 0);
      }
      // online softmax update (per q-row)
#pragma unroll
      for (int i = 0; i < 4; ++i) {
        float cm = fmaxf(fmaxf(acc4[0][i], acc4[1][i]), fmaxf(acc4[2][i], acc4[3][i]));
#pragma unroll
        for (int m2 = 1; m2 <= 8; m2 <<= 1) cm = fmaxf(cm, __shfl_xor(cm, m2, 64));
        cm *= SCALE_;
        float mn = fmaxf(m_[i], cm);
        float r = __expf(m_[i] - mn);
        float s = 0.f;
#pragma unroll
        for (int j = 0; j < 4; ++j) {
          int key = ch*64 + j*16 + col;
          float msk = 1.f;
          if (rowTpl[i] && key >= 129) msk = sd[key - 129];
          if (rowSearch[i] && key >= 1 && key <= 128) msk = sdq[i];
          float a = __expf(acc4[j][i]*SCALE_ - mn) * msk;
          acc4[j][i] = a;
          s += a;
        }
#pragma unroll
        for (int m2 = 1; m2 <= 8; m2 <<= 1) s += __shfl_xor(s, m2, 64);
        l_[i] = l_[i]*r + s;
        m_[i] = mn;
#pragma unroll
        for (int nt = 0; nt < 4; ++nt) oc[nt][i] *= r;
      }
      // PV: two 32-key steps through per-wave pst staging
#pragma unroll
      for (int st = 0; st < 2; ++st) {
#pragma unroll
        for (int i = 0; i < 4; ++i) {
          pst[wave][quad*4 + i][col]      = f2b(acc4[st*2][i]);
          pst[wave][quad*4 + i][16 + col] = f2b(acc4[st*2 + 1][i]);
        }
        short8 pa = *(const short8*)&pst[wave][col][quad*8];
        int step = ch*2 + st;
#pragma unroll
        for (int nt = 0; nt < 4; ++nt) {
          int d = nt*16 + col;
          int c = step*4 + quad;                      // < 48 always here
          int cs = (c & ~7) | ((c + (d >> 3)) & 7);
          short8 bv = *(const short8*)&vsT[d*424 + cs*8];
          oc[nt] = __builtin_amdgcn_mfma_f32_16x16x32_bf16(pa, bv, oc[nt], 0, 0, 0);
        }
      }
    }

    // epilogue chunk: key 384 (only valid lane col==0) + PV step 12 (keys 384..415)
    {
      const u16* kp = Kb + (size_t)384*2304;
      short8 b0 = *(const short8*)(kp + quad*8);
      short8 b1 = *(const short8*)(kp + 32 + quad*8);
      f32x4 accE = z4;
      accE = __builtin_amdgcn_mfma_f32_16x16x32_bf16(aq0, b0, accE, 0, 0, 0);
      accE = __builtin_amdgcn_mfma_f32_16x16x32_bf16(aq1, b1, accE, 0, 0, 0);
#pragma unroll
      for (int i = 0; i < 4; ++i) {
        float cm = (col == 0) ? accE[i] : -1e30f;
#pragma unroll
        for (int m2 = 1; m2 <= 8; m2 <<= 1) cm = fmaxf(cm, __shfl_xor(cm, m2, 64));
        cm *= SCALE_;
        float mn = fmaxf(m_[i], cm);
        float r = __expf(m_[i] - mn);
        float msk = rowTpl[i] ? sd[255] : 1.f;  // key 384 -> sd[384-129]; search rows unmasked
        float a = (col == 0) ? __expf(accE[i]*SCALE_ - mn) * msk : 0.f;
        float s = a;
#pragma unroll
        for (int m2 = 1; m2 <= 8; m2 <<= 1) s += __shfl_xor(s, m2, 64);
        l_[i] = l_[i]*r + s;
        m_[i] = mn;
#pragma unroll
        for (int nt = 0; nt < 4; ++nt) oc[nt][i] *= r;
        accE[i] = a;
      }
#pragma unroll
      for (int i = 0; i < 4; ++i) {
        pst[wave][quad*4 + i][col]      = f2b(accE[i]);
        pst[wave][quad*4 + i][16 + col] = 0;
      }
      short8 pa = *(const short8*)&pst[wave][col][quad*8];
#pragma unroll
      for (int nt = 0; nt < 4; ++nt) {
        int d = nt*16 + col;
        short8 bv = *(const short8*)&vsT[d*424 + (48 + quad)*8];  // unswizzled region
        oc[nt] = __builtin_amdgcn_mfma_f32_16x16x32_bf16(pa, bv, oc[nt], 0, 0, 0);
      }
    }

    // normalize + eps/Nq term, write out
    const float epsn = EPS_ / 321.f;
#pragma unroll
    for (int i = 0; i < 4; ++i) {
      float invv = 1.f / (l_[i] + EPS_);
      int qn = t*16 + quad*4 + i;
      if (qn <= 320) {
#pragma unroll
        for (int nt = 0; nt < 4; ++nt) {
          float val = (oc[nt][i] + epsn * vsum[nt*16 + col]) * invv;
          O[((size_t)(b*NQ + qn))*CDIM + h*HD + nt*16 + col] = f2b(val);
        }
      }
    }
  }
}

extern "C" void kernel_launch(void* const* d_in, const int* in_sizes, int n_in,
                              void* d_out, int out_size, void* d_ws, size_t ws_size,
                              hipStream_t stream) {
  const float* x      = (const float*)d_in[0];
  const float* qkv_w  = (const float*)d_in[2];
  const float* qkv_b  = (const float*)d_in[3];
  const float* proj_w = (const float*)d_in[4];
  const float* proj_b = (const float*)d_in[5];
  const float* dp1_w  = (const float*)d_in[6];
  const float* dp1_b  = (const float*)d_in[7];
  const float* dp2_w  = (const float*)d_in[8];
  const float* dp2_b  = (const float*)d_in[9];
  const float* dp3_w  = (const float*)d_in[10];
  const float* dp3_b  = (const float*)d_in[11];
  float* out = (float*)d_out;

  char* ws = (char*)d_ws;
  size_t off = 0;
  auto alloc = [&](size_t bytes) -> void* {
    void* p = ws + off;
    off += (bytes + 255) & ~(size_t)255;
    return p;
  };
  u16*  xb      = (u16*)alloc((size_t)MQ * CDIM * 2);       // 37.8 MB
  u16*  qkv_wb  = (u16*)alloc((size_t)2304 * CDIM * 2);     // 3.5 MB
  u16*  proj_wb = (u16*)alloc((size_t)CDIM * CDIM * 2);     // 1.2 MB
  u16*  qkvb    = (u16*)alloc((size_t)MQ * 2304 * 2);       // 113.5 MB
  u16*  Obuf    = (u16*)alloc((size_t)MP * CDIM * 2);       // 31.6 MB
  float* tgt    = (float*)alloc((size_t)B_ * CDIM * 4);
  float* tb     = (float*)alloc((size_t)B_ * 384 * 4);      // per-batch dp1 tgt-term bias
  float* h1     = (float*)alloc((size_t)MD * 384 * 4);      // 25.2 MB
  float* h2     = (float*)alloc((size_t)MD * 192 * 4);      // 12.6 MB
  float* sdec   = (float*)alloc((size_t)MD * 4);

  // converts
  {
    int n4 = MQ * CDIM / 4;
    k_convert4<<<dim3((n4 + 255)/256), dim3(256), 0, stream>>>((const float4*)x, (ushort4*)xb, n4);
  }
  {
    int n4 = 2304 * CDIM / 4;
    k_convert4<<<dim3((n4 + 255)/256), dim3(256), 0, stream>>>((const float4*)qkv_w, (ushort4*)qkv_wb, n4);
  }
  {
    int n4 = CDIM * CDIM / 4;
    k_convert4<<<dim3((n4 + 255)/256), dim3(256), 0, stream>>>((const float4*)proj_w, (ushort4*)proj_wb, n4);
  }
  k_tgt<<<dim3(B_), dim3(CDIM), 0, stream>>>(x, tgt);

  // qkv = x @ qkv_w.T + qkv_b  (bf16 out)
  k_gemm128<<<dim3(2304/128, (MQ + 127)/128), dim3(256), 0, stream>>>(xb, qkv_wb, qkv_b, qkvb, (float*)nullptr,
                                                                      MQ, 2304, CDIM, 0);
  // decision path (fp32):
  k_gemm_f32<<<dim3(384/64, 1), dim3(256), 0, stream>>>(tgt, nullptr, dp1_w + 768, 1536, dp1_b, tb,
                                                        B_, 384, CDIM, 0, 0, 0);
  k_gemm_f32<<<dim3(384/64, MD/128), dim3(256), 0, stream>>>(nullptr, x, dp1_w, 1536, tb, h1,
                                                             MD, 384, CDIM, 1, 1, 1);
  k_gemm_f32<<<dim3(192/64, MD/128), dim3(256), 0, stream>>>(h1, nullptr, dp2_w, 384, dp2_b, h2,
                                                             MD, 192, 384, 0, 1, 0);
  k_decision<<<dim3(MD/256), dim3(256), 0, stream>>>(h2, dp3_w, dp3_b, sdec);

  // attention (512 threads / 8 waves per block)
  k_attn<<<dim3(B_, NH), dim3(512), 0, stream>>>(qkvb, sdec, Obuf);

  // out = O @ proj_w.T + proj_b (fp32 out)
  k_gemm128<<<dim3(CDIM/128, (MP + 127)/128), dim3(256), 0, stream>>>(Obuf, proj_wb, proj_b, (u16*)nullptr, out,
                                                                      MP, CDIM, CDIM, 1);
}

// Round 2
// 833.345 us; speedup vs baseline: 1.0307x; 1.0307x over previous
//
#include <hip/hip_runtime.h>
#include <cmath>

typedef unsigned short u16;
typedef unsigned int u32;
typedef __attribute__((ext_vector_type(8))) short short8;
typedef __attribute__((ext_vector_type(4))) float f32x4;

#define B_    64
#define NV    385
#define CDIM  768
#define NQ    321
#define SFL   256
#define NH    12
#define HD    64
#define MQ    (B_*NV)   /* 24640 */
#define MP    (B_*NQ)   /* 20544 */
#define MD    (B_*SFL)  /* 16384 */
#define SCALE_ 0.125f
#define EPS_   1e-6f

__device__ __forceinline__ u16 f2b(float f) {
  u32 x = __float_as_uint(f);
  return (u16)((x + 0x7FFFu + ((x >> 16) & 1u)) >> 16);
}

__device__ __forceinline__ void gload_lds16(const void* g, void* l) {
  __builtin_amdgcn_global_load_lds(
      (const __attribute__((address_space(1))) u32*)g,
      (__attribute__((address_space(3))) u32*)l,
      16, 0, 0);
}

// ---------------- fp32 -> bf16 convert (vectorized) ----------------
__global__ void k_convert4(const float4* __restrict__ in, ushort4* __restrict__ out, int n4) {
  int i = blockIdx.x * blockDim.x + threadIdx.x;
  if (i < n4) {
    float4 v = in[i];
    ushort4 o;
    o.x = f2b(v.x); o.y = f2b(v.y); o.z = f2b(v.z); o.w = f2b(v.w);
    out[i] = o;
  }
}

// ---------------- tgt_rep = mean over x[:, 65:129, :] ----------------
__global__ void k_tgt(const float* __restrict__ x, float* __restrict__ tgt) {
  int b = blockIdx.x, c = threadIdx.x; // block = 768 threads
  float s = 0.f;
  for (int j = 0; j < 64; ++j) s += x[((size_t)(b*NV + 65 + j))*CDIM + c];
  tgt[b*CDIM + c] = s * (1.f/64.f);
}

// ---------------- 128x128 bf16 MFMA GEMM, BK=64, XOR-swizzled LDS ----------------
// mode 0 -> qkv path: scatter bf16 C into head-major Qh/Kh/Vh [h][b][n][64]
// mode 1 -> f32 out (direct, used for proj)
__global__ __launch_bounds__(256) void k_gemm128(const u16* __restrict__ A, const u16* __restrict__ W,
                                                 const float* __restrict__ bias,
                                                 u16* __restrict__ Qh, u16* __restrict__ Kh, u16* __restrict__ Vh,
                                                 float* __restrict__ Cf,
                                                 int M, int N, int K, int mode) {
  __shared__ __align__(16) u16 sbuf[128*128];  // 32 KB: As=sbuf[0:8192), Ws=sbuf[8192:16384)
  u16* As = sbuf;
  u16* Ws = sbuf + 8192;
  int tid = threadIdx.x;
  int wave = tid >> 6, lane = tid & 63;
  int quad = lane >> 4, col = lane & 15;
  int m0 = blockIdx.y * 128, n0 = blockIdx.x * 128;

  const u16* pa[4];
  const u16* pb[4];
#pragma unroll
  for (int p = 0; p < 4; ++p) {
    int c = p*256 + tid;
    int row = c >> 3;
    int sg = (c & 7) ^ (row & 7);          // XOR swizzle (source-side)
    pa[p] = A + (size_t)min(m0 + row, M - 1) * K + sg*8;
    pb[p] = W + (size_t)(n0 + row) * K + sg*8;
  }

  int wm = (wave >> 1) * 64, wn = (wave & 1) * 64;
  f32x4 acc[4][4];
  f32x4 z4 = {0.f, 0.f, 0.f, 0.f};
#pragma unroll
  for (int i = 0; i < 4; ++i)
#pragma unroll
    for (int j = 0; j < 4; ++j) acc[i][j] = z4;

  for (int k0 = 0; k0 < K; k0 += 64) {
#pragma unroll
    for (int p = 0; p < 4; ++p) {
      gload_lds16(pa[p], &As[(p*256 + wave*64) * 8]);
      gload_lds16(pb[p], &Ws[(p*256 + wave*64) * 8]);
      pa[p] += 64; pb[p] += 64;
    }
    __syncthreads();

#pragma unroll
    for (int kk = 0; kk < 2; ++kk) {
      int sr = quad + kk*4;                // 16B chunk index within the 64-u16 row
      short8 af[4], bf[4];
#pragma unroll
      for (int i = 0; i < 4; ++i) {
        int row = wm + i*16 + col;
        af[i] = *(const short8*)&As[row*64 + ((sr ^ (row & 7)) * 8)];
      }
#pragma unroll
      for (int j = 0; j < 4; ++j) {
        int row = wn + j*16 + col;
        bf[j] = *(const short8*)&Ws[row*64 + ((sr ^ (row & 7)) * 8)];
      }
#pragma unroll
      for (int i = 0; i < 4; ++i)
#pragma unroll
        for (int j = 0; j < 4; ++j)
          acc[i][j] = __builtin_amdgcn_mfma_f32_16x16x32_bf16(af[i], bf[j], acc[i][j], 0, 0, 0);
    }
    __syncthreads();
  }

  if (mode == 0) {
    // stage C-tile (bf16) in sbuf[128][128], then scatter to head-major Q/K/V
#pragma unroll
    for (int j = 0; j < 4; ++j) {
      int cc = wn + j*16 + col;
      float bv = bias ? bias[n0 + cc] : 0.f;
#pragma unroll
      for (int i = 0; i < 4; ++i)
#pragma unroll
        for (int ii = 0; ii < 4; ++ii) {
          int row = wm + i*16 + quad*4 + ii;
          sbuf[row*128 + cc] = f2b(acc[i][j][ii] + bv);
        }
    }
    __syncthreads();
#pragma unroll
    for (int q = 0; q < 8; ++q) {
      int idx = q*256 + tid;
      int row = idx >> 4, c16 = idx & 15;
      int mg = m0 + row;
      if (mg < M) {
        int n = n0 + c16*8;
        int which = n / 768;               // 128-col tiles never straddle a 768 boundary
        int rem = n - which*768;
        int hh = rem >> 6, d0 = rem & 63;
        int bb = mg / NV, nn = mg - bb*NV;
        u16* dst = (which == 0) ? Qh : (which == 1) ? Kh : Vh;
        *(float4*)(dst + (((size_t)hh*B_ + bb)*NV + nn)*64 + d0) = *(const float4*)&sbuf[row*128 + c16*8];
      }
    }
  } else {
#pragma unroll
    for (int j = 0; j < 4; ++j) {
      int cc = n0 + wn + j*16 + col;
      float bv = bias ? bias[cc] : 0.f;
#pragma unroll
      for (int i = 0; i < 4; ++i) {
        int r = m0 + wm + i*16 + quad*4;
#pragma unroll
        for (int ii = 0; ii < 4; ++ii) {
          if (r + ii < M) Cf[(size_t)(r + ii) * N + cc] = acc[i][j][ii] + bv;
        }
      }
    }
  }
}

// ---------------- fp32 GEMM v2 (decision path stays fp32) ----------------
__device__ __forceinline__ float gelu_exact(float x) {
  return 0.5f * x * (1.f + erff(x * 0.70710678118654752f));
}
__global__ __launch_bounds__(256) void k_gemm_f32(const float* __restrict__ A,
                                                  const float* __restrict__ x,
                                                  const float* __restrict__ W, int ldw,
                                                  const float* __restrict__ bias,
                                                  float* __restrict__ C, int M, int N, int K,
                                                  int gather, int gelu, int bias2d) {
  __shared__ __align__(16) float As[16][132];
  __shared__ __align__(16) float Ws[16][68];
  int tid = threadIdx.x;
  int tx = tid & 15, ty = tid >> 4;
  int n0 = blockIdx.x * 64, m0 = blockIdx.y * 128;
  float acc[8][4] = {};

  for (int k0 = 0; k0 < K; k0 += 16) {
#pragma unroll
    for (int p = 0; p < 2; ++p) {
      int f = p * 256 + tid;
      int row = f >> 2, kc = (f & 3) * 4;
      float4 v;
      if (gather) {
        int m = m0 + row;
        int b = m >> 8, s2 = m & 255;
        v = *(const float4*)(x + ((size_t)(b*NV + 129 + s2))*CDIM + k0 + kc);
      } else {
        int m = min(m0 + row, M - 1);
        v = *(const float4*)(A + (size_t)m * K + k0 + kc);
      }
      As[kc+0][row] = v.x; As[kc+1][row] = v.y; As[kc+2][row] = v.z; As[kc+3][row] = v.w;
    }
    {
      int row = tid >> 2, kc = (tid & 3) * 4;
      float4 wv = *(const float4*)(W + (size_t)(n0 + row) * ldw + k0 + kc);
      Ws[kc+0][row] = wv.x; Ws[kc+1][row] = wv.y; Ws[kc+2][row] = wv.z; Ws[kc+3][row] = wv.w;
    }
    __syncthreads();
#pragma unroll
    for (int k2 = 0; k2 < 16; ++k2) {
      float4 a0 = *(const float4*)&As[k2][ty*8];
      float4 a1 = *(const float4*)&As[k2][ty*8 + 4];
      float4 wv = *(const float4*)&Ws[k2][tx*4];
      float a_[8] = {a0.x, a0.y, a0.z, a0.w, a1.x, a1.y, a1.z, a1.w};
      float w_[4] = {wv.x, wv.y, wv.z, wv.w};
#pragma unroll
      for (int i = 0; i < 8; ++i)
#pragma unroll
        for (int j = 0; j < 4; ++j) acc[i][j] += a_[i] * w_[j];
    }
    __syncthreads();
  }
#pragma unroll
  for (int i = 0; i < 8; ++i) {
    int r = m0 + ty*8 + i;
    if (r < M) {
      float4 o;
      float* op = (float*)&o;
#pragma unroll
      for (int j = 0; j < 4; ++j) {
        int n = n0 + tx*4 + j;
        float bv = bias2d ? bias[(size_t)(r >> 8) * N + n] : bias[n];
        float v = acc[i][j] + bv;
        op[j] = gelu ? gelu_exact(v) : v;
      }
      *(float4*)(C + (size_t)r * N + n0 + tx*4) = o;
    }
  }
}

// ---------------- decision: argmax of (h2 @ dp3_w.T + dp3_b), fp32 ----------------
__global__ void k_decision(const float* __restrict__ h2, const float* __restrict__ w3,
                           const float* __restrict__ b3, float* __restrict__ sdec) {
  int r = blockIdx.x * blockDim.x + threadIdx.x; // 16384 rows
  const float* hp = h2 + (size_t)r * 192;
  float l0 = b3[0], l1 = b3[1];
  for (int k = 0; k < 192; ++k) { float h = hp[k]; l0 += h * w3[k]; l1 += h * w3[192 + k]; }
  sdec[r] = (l1 > l0) ? 1.f : 0.f; // jnp.argmax ties -> 0
}

// ---------------- attention v3: head-major Q/K/V, coalesced loads ----------------
// Q/K/V layout: [h][b][n][64] bf16. K-fragment loads now touch 16 contiguous 128B rows
// per wave instruction (was 64 scattered 4.6KB-strided lines) -> ~8x fewer VMEM
// transactions. V staging is one coalesced short8 read/thread + bank-clean LDS scatter.
__global__ __launch_bounds__(512, 4) void k_attn(const u16* __restrict__ Qh, const u16* __restrict__ Kh,
                                                 const u16* __restrict__ Vh, const float* __restrict__ sdec,
                                                 u16* __restrict__ O) {
  __shared__ __align__(16) u16 vsT[64*424];    // V^T swizzled: (d,n) at d*424 + cs*8 + (n&7)
  __shared__ __align__(16) u16 pst[8][16][40]; // per-wave P staging (16 rows x 32 keys, stride 40)
  __shared__ float sd[256];
  __shared__ float vpart[8][64];
  __shared__ float vsum[64];
  int b = blockIdx.x, h = blockIdx.y;
  int tid = threadIdx.x;
  int wave = tid >> 6, lane = tid & 63;
  int quad = lane >> 4, col = lane & 15;

  size_t base = ((size_t)(h*B_ + b))*NV*64;
  const u16* Qb = Qh + base;
  const u16* Kb = Kh + base;
  const u16* Vb = Vh + base;

  if (tid < 256) sd[tid] = sdec[b*SFL + tid];

  // zero-fill key range [385, 424) (chunks >= 48 are unswizzled)
  for (int i = tid; i < 64*39; i += 512) {
    int d = i / 39, n = 385 + (i - d*39);
    vsT[d*424 + n] = 0;
  }
  // transpose-stage V: coalesced 16B read, 8 u16 LDS writes (chunk-rotation swizzle)
  for (int idx = tid; idx < NV*8; idx += 512) {
    int n = idx >> 3, seg = idx & 7;
    short8 v = *(const short8*)(Vb + (size_t)n*64 + seg*8);
    int c = n >> 3;
    int cs = (c < 48) ? ((c & ~7) | ((c + seg) & 7)) : c;
    int b2 = cs*8 + (n & 7);
#pragma unroll
    for (int j = 0; j < 8; ++j)
      vsT[(seg*8 + j)*424 + b2] = ((const u16*)&v)[j];
  }
  __syncthreads();

  // vsum[d] = sum over keys 0..384 of V[n][d] (for the eps/Nq term)
  {
    int d = tid & 63, part = tid >> 6;
    int n_lo = part*49, n_hi = min(n_lo + 49, 385);
    float s = 0.f;
    for (int n = n_lo; n < n_hi; ++n) {
      int c = n >> 3;
      int cs = (c < 48) ? ((c & ~7) | ((c + (d >> 3)) & 7)) : c;
      s += __uint_as_float((u32)vsT[d*424 + cs*8 + (n & 7)] << 16);
    }
    vpart[part][d] = s;
  }
  __syncthreads();
  if (tid < 64) {
    float s = 0.f;
#pragma unroll
    for (int p = 0; p < 8; ++p) s += vpart[p][tid];
    vsum[tid] = s;
  }
  __syncthreads();

  const f32x4 z4 = {0.f, 0.f, 0.f, 0.f};

  for (int t = wave; t < 21; t += 8) {
    int qn_a = t*16 + col;
    int pos = (qn_a == 0) ? 0 : (min(qn_a, 320) + 64);
    const u16* qp = Qb + (size_t)pos*64 + quad*8;
    short8 aq0 = *(const short8*)(qp);
    short8 aq1 = *(const short8*)(qp + 32);

    float m_[4], l_[4];
    bool rowTpl[4], rowSearch[4];
    float sdq[4];
#pragma unroll
    for (int i = 0; i < 4; ++i) {
      m_[i] = -1e30f; l_[i] = 0.f;
      int qn = t*16 + quad*4 + i;
      rowTpl[i] = (qn >= 1 && qn <= 64);
      rowSearch[i] = (qn >= 65);
      sdq[i] = rowSearch[i] ? sd[min(qn - 65, 255)] : 1.f;
    }
    f32x4 oc[4];
#pragma unroll
    for (int nt = 0; nt < 4; ++nt) oc[nt] = z4;

    // 6 full chunks of 64 keys (0..383)
    for (int ch = 0; ch < 6; ++ch) {
      f32x4 acc4[4];
#pragma unroll
      for (int j = 0; j < 4; ++j) acc4[j] = z4;
#pragma unroll
      for (int j = 0; j < 4; ++j) {
        const u16* kp = Kb + (size_t)(ch*64 + j*16 + col)*64;
        short8 b0 = *(const short8*)(kp + quad*8);
        short8 b1 = *(const short8*)(kp + 32 + quad*8);
        acc4[j] = __builtin_amdgcn_mfma_f32_16x16x32_bf16(aq0, b0, acc4[j], 0, 0, 0);
        acc4[j] = __builtin_amdgcn_mfma_f32_16x16x32_bf16(aq1, b1, acc4[j], 0, 0, 0);
      }
      // online softmax update (per q-row)
#pragma unroll
      for (int i = 0; i < 4; ++i) {
        float cm = fmaxf(fmaxf(acc4[0][i], acc4[1][i]), fmaxf(acc4[2][i], acc4[3][i]));
#pragma unroll
        for (int m2 = 1; m2 <= 8; m2 <<= 1) cm = fmaxf(cm, __shfl_xor(cm, m2, 64));
        cm *= SCALE_;
        float mn = fmaxf(m_[i], cm);
        float r = __expf(m_[i] - mn);
        float s = 0.f;
#pragma unroll
        for (int j = 0; j < 4; ++j) {
          int key = ch*64 + j*16 + col;
          float msk = 1.f;
          if (rowTpl[i] && key >= 129) msk = sd[key - 129];
          if (rowSearch[i] && key >= 1 && key <= 128) msk = sdq[i];
          float a = __expf(acc4[j][i]*SCALE_ - mn) * msk;
          acc4[j][i] = a;
          s += a;
        }
#pragma unroll
        for (int m2 = 1; m2 <= 8; m2 <<= 1) s += __shfl_xor(s, m2, 64);
        l_[i] = l_[i]*r + s;
        m_[i] = mn;
#pragma unroll
        for (int nt = 0; nt < 4; ++nt) oc[nt][i] *= r;
      }
      // PV: two 32-key steps through per-wave pst staging
#pragma unroll
      for (int st = 0; st < 2; ++st) {
#pragma unroll
        for (int i = 0; i < 4; ++i) {
          pst[wave][quad*4 + i][col]      = f2b(acc4[st*2][i]);
          pst[wave][quad*4 + i][16 + col] = f2b(acc4[st*2 + 1][i]);
        }
        short8 pa = *(const short8*)&pst[wave][col][quad*8];
        int step = ch*2 + st;
#pragma unroll
        for (int nt = 0; nt < 4; ++nt) {
          int d = nt*16 + col;
          int c = step*4 + quad;                      // < 48 always here
          int cs = (c & ~7) | ((c + (d >> 3)) & 7);
          short8 bv = *(const short8*)&vsT[d*424 + cs*8];
          oc[nt] = __builtin_amdgcn_mfma_f32_16x16x32_bf16(pa, bv, oc[nt], 0, 0, 0);
        }
      }
    }

    // epilogue chunk: key 384 (only valid lane col==0) + PV step 12
    {
      const u16* kp = Kb + (size_t)384*64;
      short8 b0 = *(const short8*)(kp + quad*8);
      short8 b1 = *(const short8*)(kp + 32 + quad*8);
      f32x4 accE = z4;
      accE = __builtin_amdgcn_mfma_f32_16x16x32_bf16(aq0, b0, accE, 0, 0, 0);
      accE = __builtin_amdgcn_mfma_f32_16x16x32_bf16(aq1, b1, accE, 0, 0, 0);
#pragma unroll
      for (int i = 0; i < 4; ++i) {
        float cm = (col == 0) ? accE[i] : -1e30f;
#pragma unroll
        for (int m2 = 1; m2 <= 8; m2 <<= 1) cm = fmaxf(cm, __shfl_xor(cm, m2, 64));
        cm *= SCALE_;
        float mn = fmaxf(m_[i], cm);
        float r = __expf(m_[i] - mn);
        float msk = rowTpl[i] ? sd[255] : 1.f;
        float a = (col == 0) ? __expf(accE[i]*SCALE_ - mn) * msk : 0.f;
        float s = a;
#pragma unroll
        for (int m2 = 1; m2 <= 8; m2 <<= 1) s += __shfl_xor(s, m2, 64);
        l_[i] = l_[i]*r + s;
        m_[i] = mn;
#pragma unroll
        for (int nt = 0; nt < 4; ++nt) oc[nt][i] *= r;
        accE[i] = a;
      }
#pragma unroll
      for (int i = 0; i < 4; ++i) {
        pst[wave][quad*4 + i][col]      = f2b(accE[i]);
        pst[wave][quad*4 + i][16 + col] = 0;
      }
      short8 pa = *(const short8*)&pst[wave][col][quad*8];
#pragma unroll
      for (int nt = 0; nt < 4; ++nt) {
        int d = nt*16 + col;
        short8 bv = *(const short8*)&vsT[d*424 + (48 + quad)*8];  // unswizzled region
        oc[nt] = __builtin_amdgcn_mfma_f32_16x16x32_bf16(pa, bv, oc[nt], 0, 0, 0);
      }
    }

    // normalize + eps/Nq term, write out
    const float epsn = EPS_ / 321.f;
#pragma unroll
    for (int i = 0; i < 4; ++i) {
      float invv = 1.f / (l_[i] + EPS_);
      int qn = t*16 + quad*4 + i;
      if (qn <= 320) {
#pragma unroll
        for (int nt = 0; nt < 4; ++nt) {
          float val = (oc[nt][i] + epsn * vsum[nt*16 + col]) * invv;
          O[((size_t)(b*NQ + qn))*CDIM + h*HD + nt*16 + col] = f2b(val);
        }
      }
    }
  }
}

extern "C" void kernel_launch(void* const* d_in, const int* in_sizes, int n_in,
                              void* d_out, int out_size, void* d_ws, size_t ws_size,
                              hipStream_t stream) {
  const float* x      = (const float*)d_in[0];
  const float* qkv_w  = (const float*)d_in[2];
  const float* qkv_b  = (const float*)d_in[3];
  const float* proj_w = (const float*)d_in[4];
  const float* proj_b = (const float*)d_in[5];
  const float* dp1_w  = (const float*)d_in[6];
  const float* dp1_b  = (const float*)d_in[7];
  const float* dp2_w  = (const float*)d_in[8];
  const float* dp2_b  = (const float*)d_in[9];
  const float* dp3_w  = (const float*)d_in[10];
  const float* dp3_b  = (const float*)d_in[11];
  float* out = (float*)d_out;

  char* ws = (char*)d_ws;
  size_t off = 0;
  auto alloc = [&](size_t bytes) -> void* {
    void* p = ws + off;
    off += (bytes + 255) & ~(size_t)255;
    return p;
  };
  u16*  xb      = (u16*)alloc((size_t)MQ * CDIM * 2);       // 37.8 MB
  u16*  qkv_wb  = (u16*)alloc((size_t)2304 * CDIM * 2);     // 3.5 MB
  u16*  proj_wb = (u16*)alloc((size_t)CDIM * CDIM * 2);     // 1.2 MB
  u16*  qh      = (u16*)alloc((size_t)NH * B_ * NV * 64 * 2); // 37.8 MB
  u16*  kh      = (u16*)alloc((size_t)NH * B_ * NV * 64 * 2); // 37.8 MB
  u16*  vh      = (u16*)alloc((size_t)NH * B_ * NV * 64 * 2); // 37.8 MB
  u16*  Obuf    = (u16*)alloc((size_t)MP * CDIM * 2);       // 31.6 MB
  float* tgt    = (float*)alloc((size_t)B_ * CDIM * 4);
  float* tb     = (float*)alloc((size_t)B_ * 384 * 4);      // per-batch dp1 tgt-term bias
  float* h1     = (float*)alloc((size_t)MD * 384 * 4);      // 25.2 MB
  float* h2     = (float*)alloc((size_t)MD * 192 * 4);      // 12.6 MB
  float* sdec   = (float*)alloc((size_t)MD * 4);

  // converts
  {
    int n4 = MQ * CDIM / 4;
    k_convert4<<<dim3((n4 + 255)/256), dim3(256), 0, stream>>>((const float4*)x, (ushort4*)xb, n4);
  }
  {
    int n4 = 2304 * CDIM / 4;
    k_convert4<<<dim3((n4 + 255)/256), dim3(256), 0, stream>>>((const float4*)qkv_w, (ushort4*)qkv_wb, n4);
  }
  {
    int n4 = CDIM * CDIM / 4;
    k_convert4<<<dim3((n4 + 255)/256), dim3(256), 0, stream>>>((const float4*)proj_w, (ushort4*)proj_wb, n4);
  }
  k_tgt<<<dim3(B_), dim3(CDIM), 0, stream>>>(x, tgt);

  // qkv = x @ qkv_w.T + qkv_b  (bf16 out, scattered to head-major Q/K/V)
  k_gemm128<<<dim3(2304/128, (MQ + 127)/128), dim3(256), 0, stream>>>(xb, qkv_wb, qkv_b, qh, kh, vh,
                                                                      (float*)nullptr, MQ, 2304, CDIM, 0);
  // decision path (fp32):
  k_gemm_f32<<<dim3(384/64, 1), dim3(256), 0, stream>>>(tgt, nullptr, dp1_w + 768, 1536, dp1_b, tb,
                                                        B_, 384, CDIM, 0, 0, 0);
  k_gemm_f32<<<dim3(384/64, MD/128), dim3(256), 0, stream>>>(nullptr, x, dp1_w, 1536, tb, h1,
                                                             MD, 384, CDIM, 1, 1, 1);
  k_gemm_f32<<<dim3(192/64, MD/128), dim3(256), 0, stream>>>(h1, nullptr, dp2_w, 384, dp2_b, h2,
                                                             MD, 192, 384, 0, 1, 0);
  k_decision<<<dim3(MD/256), dim3(256), 0, stream>>>(h2, dp3_w, dp3_b, sdec);

  // attention (512 threads / 8 waves per block)
  k_attn<<<dim3(B_, NH), dim3(512), 0, stream>>>(qh, kh, vh, sdec, Obuf);

  // out = O @ proj_w.T + proj_b (fp32 out)
  k_gemm128<<<dim3(CDIM/128, (MP + 127)/128), dim3(256), 0, stream>>>(Obuf, proj_wb, proj_b,
                                                                      nullptr, nullptr, nullptr, out,
                                                                      MP, CDIM, CDIM, 1);
}

// Round 4
// 788.762 us; speedup vs baseline: 1.0889x; 1.0565x over previous
//
#include <hip/hip_runtime.h>
#include <cmath>

typedef unsigned short u16;
typedef unsigned int u32;
typedef __attribute__((ext_vector_type(8))) short short8;
typedef __attribute__((ext_vector_type(4))) float f32x4;

#define B_    64
#define NV    385
#define CDIM  768
#define NQ    321
#define SFL   256
#define NH    12
#define HD    64
#define MQ    (B_*NV)   /* 24640 */
#define MP    (B_*NQ)   /* 20544 */
#define MD    (B_*SFL)  /* 16384 */
#define SCALE_ 0.125f
#define EPS_   1e-6f

__device__ __forceinline__ u16 f2b(float f) {
  u32 x = __float_as_uint(f);
  return (u16)((x + 0x7FFFu + ((x >> 16) & 1u)) >> 16);
}

__device__ __forceinline__ void gload_lds16(const void* g, void* l) {
  __builtin_amdgcn_global_load_lds(
      (const __attribute__((address_space(1))) u32*)g,
      (__attribute__((address_space(3))) u32*)l,
      16, 0, 0);
}

// ---------------- fp32 -> bf16 convert (vectorized) ----------------
__global__ void k_convert4(const float4* __restrict__ in, ushort4* __restrict__ out, int n4) {
  int i = blockIdx.x * blockDim.x + threadIdx.x;
  if (i < n4) {
    float4 v = in[i];
    ushort4 o;
    o.x = f2b(v.x); o.y = f2b(v.y); o.z = f2b(v.z); o.w = f2b(v.w);
    out[i] = o;
  }
}

// ---------------- tgt_rep = mean over x[:, 65:129, :] ----------------
__global__ void k_tgt(const float* __restrict__ x, float* __restrict__ tgt) {
  int b = blockIdx.x, c = threadIdx.x; // block = 768 threads
  float s = 0.f;
  for (int j = 0; j < 64; ++j) s += x[((size_t)(b*NV + 65 + j))*CDIM + c];
  tgt[b*CDIM + c] = s * (1.f/64.f);
}

// ---------------- 128x128 bf16 MFMA GEMM, BK=64, XOR-swizzled LDS ----------------
// mode 0 -> qkv path: scatter bf16 C into head-major Qh/Kh/Vh [h][b][n][64]
// mode 1 -> f32 out (direct, used for proj)
__global__ __launch_bounds__(256) void k_gemm128(const u16* __restrict__ A, const u16* __restrict__ W,
                                                 const float* __restrict__ bias,
                                                 u16* __restrict__ Qh, u16* __restrict__ Kh, u16* __restrict__ Vh,
                                                 float* __restrict__ Cf,
                                                 int M, int N, int K, int mode) {
  __shared__ __align__(16) u16 sbuf[128*128];  // 32 KB: As=sbuf[0:8192), Ws=sbuf[8192:16384)
  u16* As = sbuf;
  u16* Ws = sbuf + 8192;
  int tid = threadIdx.x;
  int wave = tid >> 6, lane = tid & 63;
  int quad = lane >> 4, col = lane & 15;
  int m0 = blockIdx.y * 128, n0 = blockIdx.x * 128;

  const u16* pa[4];
  const u16* pb[4];
#pragma unroll
  for (int p = 0; p < 4; ++p) {
    int c = p*256 + tid;
    int row = c >> 3;
    int sg = (c & 7) ^ (row & 7);          // XOR swizzle (source-side)
    pa[p] = A + (size_t)min(m0 + row, M - 1) * K + sg*8;
    pb[p] = W + (size_t)(n0 + row) * K + sg*8;
  }

  int wm = (wave >> 1) * 64, wn = (wave & 1) * 64;
  f32x4 acc[4][4];
  f32x4 z4 = {0.f, 0.f, 0.f, 0.f};
#pragma unroll
  for (int i = 0; i < 4; ++i)
#pragma unroll
    for (int j = 0; j < 4; ++j) acc[i][j] = z4;

  for (int k0 = 0; k0 < K; k0 += 64) {
#pragma unroll
    for (int p = 0; p < 4; ++p) {
      gload_lds16(pa[p], &As[(p*256 + wave*64) * 8]);
      gload_lds16(pb[p], &Ws[(p*256 + wave*64) * 8]);
      pa[p] += 64; pb[p] += 64;
    }
    __syncthreads();

#pragma unroll
    for (int kk = 0; kk < 2; ++kk) {
      int sr = quad + kk*4;                // 16B chunk index within the 64-u16 row
      short8 af[4], bf[4];
#pragma unroll
      for (int i = 0; i < 4; ++i) {
        int row = wm + i*16 + col;
        af[i] = *(const short8*)&As[row*64 + ((sr ^ (row & 7)) * 8)];
      }
#pragma unroll
      for (int j = 0; j < 4; ++j) {
        int row = wn + j*16 + col;
        bf[j] = *(const short8*)&Ws[row*64 + ((sr ^ (row & 7)) * 8)];
      }
#pragma unroll
      for (int i = 0; i < 4; ++i)
#pragma unroll
        for (int j = 0; j < 4; ++j)
          acc[i][j] = __builtin_amdgcn_mfma_f32_16x16x32_bf16(af[i], bf[j], acc[i][j], 0, 0, 0);
    }
    __syncthreads();
  }

  if (mode == 0) {
    // stage C-tile (bf16) in sbuf[128][128], then scatter to head-major Q/K/V
#pragma unroll
    for (int j = 0; j < 4; ++j) {
      int cc = wn + j*16 + col;
      float bv = bias ? bias[n0 + cc] : 0.f;
#pragma unroll
      for (int i = 0; i < 4; ++i)
#pragma unroll
        for (int ii = 0; ii < 4; ++ii) {
          int row = wm + i*16 + quad*4 + ii;
          sbuf[row*128 + cc] = f2b(acc[i][j][ii] + bv);
        }
    }
    __syncthreads();
#pragma unroll
    for (int q = 0; q < 8; ++q) {
      int idx = q*256 + tid;
      int row = idx >> 4, c16 = idx & 15;
      int mg = m0 + row;
      if (mg < M) {
        int n = n0 + c16*8;
        int which = n / 768;               // 128-col tiles never straddle a 768 boundary
        int rem = n - which*768;
        int hh = rem >> 6, d0 = rem & 63;
        int bb = mg / NV, nn = mg - bb*NV;
        u16* dst = (which == 0) ? Qh : (which == 1) ? Kh : Vh;
        *(float4*)(dst + (((size_t)hh*B_ + bb)*NV + nn)*64 + d0) = *(const float4*)&sbuf[row*128 + c16*8];
      }
    }
  } else {
#pragma unroll
    for (int j = 0; j < 4; ++j) {
      int cc = n0 + wn + j*16 + col;
      float bv = bias ? bias[cc] : 0.f;
#pragma unroll
      for (int i = 0; i < 4; ++i) {
        int r = m0 + wm + i*16 + quad*4;
#pragma unroll
        for (int ii = 0; ii < 4; ++ii) {
          if (r + ii < M) Cf[(size_t)(r + ii) * N + cc] = acc[i][j][ii] + bv;
        }
      }
    }
  }
}

// ---------------- fp32 GEMM v2 (decision path stays fp32) ----------------
__device__ __forceinline__ float gelu_exact(float x) {
  return 0.5f * x * (1.f + erff(x * 0.70710678118654752f));
}
__global__ __launch_bounds__(256) void k_gemm_f32(const float* __restrict__ A,
                                                  const float* __restrict__ x,
                                                  const float* __restrict__ W, int ldw,
                                                  const float* __restrict__ bias,
                                                  float* __restrict__ C, int M, int N, int K,
                                                  int gather, int gelu, int bias2d) {
  __shared__ __align__(16) float As[16][132];
  __shared__ __align__(16) float Ws[16][68];
  int tid = threadIdx.x;
  int tx = tid & 15, ty = tid >> 4;
  int n0 = blockIdx.x * 64, m0 = blockIdx.y * 128;
  float acc[8][4] = {};

  for (int k0 = 0; k0 < K; k0 += 16) {
#pragma unroll
    for (int p = 0; p < 2; ++p) {
      int f = p * 256 + tid;
      int row = f >> 2, kc = (f & 3) * 4;
      float4 v;
      if (gather) {
        int m = m0 + row;
        int b = m >> 8, s2 = m & 255;
        v = *(const float4*)(x + ((size_t)(b*NV + 129 + s2))*CDIM + k0 + kc);
      } else {
        int m = min(m0 + row, M - 1);
        v = *(const float4*)(A + (size_t)m * K + k0 + kc);
      }
      As[kc+0][row] = v.x; As[kc+1][row] = v.y; As[kc+2][row] = v.z; As[kc+3][row] = v.w;
    }
    {
      int row = tid >> 2, kc = (tid & 3) * 4;
      float4 wv = *(const float4*)(W + (size_t)(n0 + row) * ldw + k0 + kc);
      Ws[kc+0][row] = wv.x; Ws[kc+1][row] = wv.y; Ws[kc+2][row] = wv.z; Ws[kc+3][row] = wv.w;
    }
    __syncthreads();
#pragma unroll
    for (int k2 = 0; k2 < 16; ++k2) {
      float4 a0 = *(const float4*)&As[k2][ty*8];
      float4 a1 = *(const float4*)&As[k2][ty*8 + 4];
      float4 wv = *(const float4*)&Ws[k2][tx*4];
      float a_[8] = {a0.x, a0.y, a0.z, a0.w, a1.x, a1.y, a1.z, a1.w};
      float w_[4] = {wv.x, wv.y, wv.z, wv.w};
#pragma unroll
      for (int i = 0; i < 8; ++i)
#pragma unroll
        for (int j = 0; j < 4; ++j) acc[i][j] += a_[i] * w_[j];
    }
    __syncthreads();
  }
#pragma unroll
  for (int i = 0; i < 8; ++i) {
    int r = m0 + ty*8 + i;
    if (r < M) {
      float4 o;
      float* op = (float*)&o;
#pragma unroll
      for (int j = 0; j < 4; ++j) {
        int n = n0 + tx*4 + j;
        float bv = bias2d ? bias[(size_t)(r >> 8) * N + n] : bias[n];
        float v = acc[i][j] + bv;
        op[j] = gelu ? gelu_exact(v) : v;
      }
      *(float4*)(C + (size_t)r * N + n0 + tx*4) = o;
    }
  }
}

// ---------------- decision: argmax of (h2 @ dp3_w.T + dp3_b), fp32 ----------------
__global__ void k_decision(const float* __restrict__ h2, const float* __restrict__ w3,
                           const float* __restrict__ b3, float* __restrict__ sdec) {
  int r = blockIdx.x * blockDim.x + threadIdx.x; // 16384 rows
  const float* hp = h2 + (size_t)r * 192;
  float l0 = b3[0], l1 = b3[1];
  for (int k = 0; k < 192; ++k) { float h = hp[k]; l0 += h * w3[k]; l1 += h * w3[192 + k]; }
  sdec[r] = (l1 > l0) ? 1.f : 0.f; // jnp.argmax ties -> 0
}

// ---------------- attention v5: swapped QK^T, shfl broadcasts (no LDS RAW hazards) ----------------
// v4 failed (absmax ~15 == unnormalized outputs): the rst[] LDS write->read quad-broadcast
// has no intra-thread dependency, so the compiler may reorder it; the final l_ broadcast
// read stale data (~1.0) -> no normalization. v5: all quad-broadcasts via __shfl
// (ds_bpermute, compiler-visible cross-lane dep); pst write->read pinned with a compiler
// memory fence; cvt_pk asm replaced by verified f2b packing; epilogue K-load clamped.
__global__ __launch_bounds__(512, 4) void k_attn(const u16* __restrict__ Qh, const u16* __restrict__ Kh,
                                                 const u16* __restrict__ Vh, const float* __restrict__ sdec,
                                                 u16* __restrict__ O) {
  __shared__ __align__(16) u16 vsT[64*424];    // V^T swizzled: (d,n) at d*424 + cs*8 + (n&7)
  __shared__ __align__(16) u16 pst[8][16][72]; // per-wave P staging: [q][key64], stride 72
  __shared__ float sd[256];
  __shared__ __align__(16) float sdm[416];     // template-row mask table over keys
  __shared__ float vsum[64];
  float* vpart = (float*)pst;                  // prologue alias (8*64 floats)

  int b = blockIdx.x, h = blockIdx.y;
  int tid = threadIdx.x;
  int wave = tid >> 6, lane = tid & 63;
  int quad = lane >> 4, col = lane & 15;

  size_t base = ((size_t)(h*B_ + b))*NV*64;
  const u16* Qb = Qh + base;
  const u16* Kb = Kh + base;
  const u16* Vb = Vh + base;

  if (tid < 256) sd[tid] = sdec[b*SFL + tid];
  for (int k = tid; k < 416; k += 512)
    sdm[k] = (k < 129) ? 1.f : ((k <= 384) ? sdec[b*SFL + k - 129] : 0.f);

  // zero-fill key range [385, 424) (chunks >= 48 are unswizzled)
  for (int i = tid; i < 64*39; i += 512) {
    int d = i / 39, n = 385 + (i - d*39);
    vsT[d*424 + n] = 0;
  }
  // transpose-stage V: coalesced 16B read, 8 u16 LDS writes (chunk-rotation swizzle)
  for (int idx = tid; idx < NV*8; idx += 512) {
    int n = idx >> 3, seg = idx & 7;
    short8 v = *(const short8*)(Vb + (size_t)n*64 + seg*8);
    int c = n >> 3;
    int cs = (c < 48) ? ((c & ~7) | ((c + seg) & 7)) : c;
    int b2 = cs*8 + (n & 7);
#pragma unroll
    for (int j = 0; j < 8; ++j)
      vsT[(seg*8 + j)*424 + b2] = ((const u16*)&v)[j];
  }
  __syncthreads();

  // vsum[d] = sum over keys 0..384 of V[n][d] (for the eps/Nq term)
  {
    int d = tid & 63, part = tid >> 6;
    int n_lo = part*49, n_hi = min(n_lo + 49, 385);
    float s = 0.f;
    for (int n = n_lo; n < n_hi; ++n) {
      int c = n >> 3;
      int cs = (c < 48) ? ((c & ~7) | ((c + (d >> 3)) & 7)) : c;
      s += __uint_as_float((u32)vsT[d*424 + cs*8 + (n & 7)] << 16);
    }
    vpart[part*64 + d] = s;
  }
  __syncthreads();
  if (tid < 64) {
    float s = 0.f;
#pragma unroll
    for (int p = 0; p < 8; ++p) s += vpart[p*64 + tid];
    vsum[tid] = s;
  }
  __syncthreads();

  const f32x4 z4 = {0.f, 0.f, 0.f, 0.f};
  // hoisted vsum fragments (constant across tiles)
  float vsn[4];
#pragma unroll
  for (int nt = 0; nt < 4; ++nt) vsn[nt] = vsum[nt*16 + col];

  for (int t = wave; t < 21; t += 8) {
    int qn_lane = t*16 + col;
    int pos = (qn_lane == 0) ? 0 : (min(qn_lane, 320) + 64);
    const u16* qp = Qb + (size_t)pos*64 + quad*8;
    short8 aq0 = *(const short8*)(qp);        // B-operand: Q[q=col][d=quad*8..]
    short8 aq1 = *(const short8*)(qp + 32);

    bool isTpl = (qn_lane >= 1 && qn_lane <= 64);
    bool isSearch = (qn_lane >= 65);
    float sdq = isSearch ? sd[min(qn_lane - 65, 255)] : 1.f;

    float m_ = -1e30f, l_ = 0.f;
    f32x4 oc[4];
#pragma unroll
    for (int nt = 0; nt < 4; ++nt) oc[nt] = z4;

    // 6 full chunks of 64 keys (0..383)
    for (int ch = 0; ch < 6; ++ch) {
      int key0c = ch*64;
      f32x4 acc4[4];
#pragma unroll
      for (int j = 0; j < 4; ++j) acc4[j] = z4;
#pragma unroll
      for (int j = 0; j < 4; ++j) {
        const u16* kp = Kb + (size_t)(key0c + j*16 + col)*64;  // A-operand: K[key=col][d]
        short8 k0 = *(const short8*)(kp + quad*8);
        short8 k1 = *(const short8*)(kp + 32 + quad*8);
        acc4[j] = __builtin_amdgcn_mfma_f32_16x16x32_bf16(k0, aq0, acc4[j], 0, 0, 0);
        acc4[j] = __builtin_amdgcn_mfma_f32_16x16x32_bf16(k1, aq1, acc4[j], 0, 0, 0);
      }
      // C[key][q]: lane has keys {key0c + j*16 + quad*4 + r} for its q=col.
      float cm = acc4[0][0];
#pragma unroll
      for (int j = 0; j < 4; ++j)
#pragma unroll
        for (int r = 0; r < 4; ++r)
          if (j || r) cm = fmaxf(cm, acc4[j][r]);
      cm = fmaxf(cm, __shfl_xor(cm, 16, 64));
      cm = fmaxf(cm, __shfl_xor(cm, 32, 64));
      float mn = fmaxf(m_, cm * SCALE_);
      float rnew = __expf(m_ - mn);
      m_ = mn;
      // broadcast rnew from q=col holders to the oc rows (q = quad*4 + r) via shfl
      float rb[4];
#pragma unroll
      for (int r = 0; r < 4; ++r) rb[r] = __shfl(rnew, quad*4 + r, 64);
#pragma unroll
      for (int nt = 0; nt < 4; ++nt) {
        oc[nt][0] *= rb[0]; oc[nt][1] *= rb[1]; oc[nt][2] *= rb[2]; oc[nt][3] *= rb[3];
      }

      float ssum = 0.f;
#pragma unroll
      for (int j = 0; j < 4; ++j) {
        int key0 = key0c + j*16;
        float4 tm = make_float4(1.f, 1.f, 1.f, 1.f);
        if (isTpl) tm = *(const float4*)&sdm[key0 + quad*4];
        float a[4];
        const float* tmp = (const float*)&tm;
#pragma unroll
        for (int r = 0; r < 4; ++r) {
          int key = key0 + quad*4 + r;
          float msk = isTpl ? tmp[r]
                            : ((isSearch && key >= 1 && key <= 128) ? sdq : 1.f);
          a[r] = __expf(fmaf(acc4[j][r], SCALE_, -mn)) * msk;
          ssum += a[r];
        }
        uint2 pk;
        pk.x = (u32)f2b(a[0]) | ((u32)f2b(a[1]) << 16);
        pk.y = (u32)f2b(a[2]) | ((u32)f2b(a[3]) << 16);
        *(uint2*)&pst[wave][col][j*16 + quad*4] = pk;
      }
      ssum += __shfl_xor(ssum, 16, 64);
      ssum += __shfl_xor(ssum, 32, 64);
      l_ = l_ * rnew + ssum;

      asm volatile("" ::: "memory");   // pin P-writes before fragment reads
      // PV: two 32-key steps; A = P[q=col][k], B = V^T[k][d=col]
#pragma unroll
      for (int st = 0; st < 2; ++st) {
        short8 pa = *(const short8*)&pst[wave][col][st*32 + quad*8];
        int step = ch*2 + st;
#pragma unroll
        for (int nt = 0; nt < 4; ++nt) {
          int d = nt*16 + col;
          int c = step*4 + quad;                      // < 48 always here
          int cs = (c & ~7) | ((c + (d >> 3)) & 7);
          short8 bv = *(const short8*)&vsT[d*424 + cs*8];
          oc[nt] = __builtin_amdgcn_mfma_f32_16x16x32_bf16(pa, bv, oc[nt], 0, 0, 0);
        }
      }
    }

    // epilogue: key 384 only. Broadcast-load K[384] into all A-rows; only C-row 0
    // (quad==0, reg 0) is kept.
    {
      const u16* kp = Kb + (size_t)384*64;
      short8 k0 = *(const short8*)(kp + quad*8);
      short8 k1 = *(const short8*)(kp + 32 + quad*8);
      f32x4 accE = z4;
      accE = __builtin_amdgcn_mfma_f32_16x16x32_bf16(k0, aq0, accE, 0, 0, 0);
      accE = __builtin_amdgcn_mfma_f32_16x16x32_bf16(k1, aq1, accE, 0, 0, 0);
      float cm = (quad == 0) ? accE[0] : -1e30f;
      cm = fmaxf(cm, __shfl_xor(cm, 16, 64));
      cm = fmaxf(cm, __shfl_xor(cm, 32, 64));
      float mn = fmaxf(m_, cm * SCALE_);
      float rnew = __expf(m_ - mn);
      m_ = mn;
      float rb[4];
#pragma unroll
      for (int r = 0; r < 4; ++r) rb[r] = __shfl(rnew, quad*4 + r, 64);
#pragma unroll
      for (int nt = 0; nt < 4; ++nt) {
        oc[nt][0] *= rb[0]; oc[nt][1] *= rb[1]; oc[nt][2] *= rb[2]; oc[nt][3] *= rb[3];
      }
      float mskE = isTpl ? sdm[384] : 1.f;  // key 384 -> sdec[255]; search rows unmasked
      float aE = (quad == 0) ? __expf(fmaf(accE[0], SCALE_, -mn)) * mskE : 0.f;
      float ssum = aE;
      ssum += __shfl_xor(ssum, 16, 64);
      ssum += __shfl_xor(ssum, 32, 64);
      l_ = l_ * rnew + ssum;

      uint2 pk;
      pk.x = (quad == 0) ? (u32)f2b(aE) : 0u;
      pk.y = 0u;
      *(uint2*)&pst[wave][col][quad*4] = pk;
      *(uint2*)&pst[wave][col][16 + quad*4] = make_uint2(0u, 0u);
      asm volatile("" ::: "memory");
      short8 pa = *(const short8*)&pst[wave][col][quad*8];
#pragma unroll
      for (int nt = 0; nt < 4; ++nt) {
        int d = nt*16 + col;
        short8 bv = *(const short8*)&vsT[d*424 + (48 + quad)*8];  // unswizzled region
        oc[nt] = __builtin_amdgcn_mfma_f32_16x16x32_bf16(pa, bv, oc[nt], 0, 0, 0);
      }
    }

    // broadcast l_ to oc rows via shfl, normalize + eps/Nq, write out
    float lb[4];
#pragma unroll
    for (int r = 0; r < 4; ++r) lb[r] = __shfl(l_, quad*4 + r, 64);
    const float epsn = EPS_ / 321.f;
#pragma unroll
    for (int r = 0; r < 4; ++r) {
      float invv = 1.f / (lb[r] + EPS_);
      int qn = t*16 + quad*4 + r;
      if (qn <= 320) {
#pragma unroll
        for (int nt = 0; nt < 4; ++nt) {
          float val = (oc[nt][r] + epsn * vsn[nt]) * invv;
          O[((size_t)(b*NQ + qn))*CDIM + h*HD + nt*16 + col] = f2b(val);
        }
      }
    }
  }
}

extern "C" void kernel_launch(void* const* d_in, const int* in_sizes, int n_in,
                              void* d_out, int out_size, void* d_ws, size_t ws_size,
                              hipStream_t stream) {
  const float* x      = (const float*)d_in[0];
  const float* qkv_w  = (const float*)d_in[2];
  const float* qkv_b  = (const float*)d_in[3];
  const float* proj_w = (const float*)d_in[4];
  const float* proj_b = (const float*)d_in[5];
  const float* dp1_w  = (const float*)d_in[6];
  const float* dp1_b  = (const float*)d_in[7];
  const float* dp2_w  = (const float*)d_in[8];
  const float* dp2_b  = (const float*)d_in[9];
  const float* dp3_w  = (const float*)d_in[10];
  const float* dp3_b  = (const float*)d_in[11];
  float* out = (float*)d_out;

  char* ws = (char*)d_ws;
  size_t off = 0;
  auto alloc = [&](size_t bytes) -> void* {
    void* p = ws + off;
    off += (bytes + 255) & ~(size_t)255;
    return p;
  };
  u16*  xb      = (u16*)alloc((size_t)MQ * CDIM * 2);       // 37.8 MB
  u16*  qkv_wb  = (u16*)alloc((size_t)2304 * CDIM * 2);     // 3.5 MB
  u16*  proj_wb = (u16*)alloc((size_t)CDIM * CDIM * 2);     // 1.2 MB
  u16*  qh      = (u16*)alloc((size_t)NH * B_ * NV * 64 * 2); // 37.8 MB
  u16*  kh      = (u16*)alloc((size_t)NH * B_ * NV * 64 * 2); // 37.8 MB
  u16*  vh      = (u16*)alloc((size_t)NH * B_ * NV * 64 * 2); // 37.8 MB
  u16*  Obuf    = (u16*)alloc((size_t)MP * CDIM * 2);       // 31.6 MB
  float* tgt    = (float*)alloc((size_t)B_ * CDIM * 4);
  float* tb     = (float*)alloc((size_t)B_ * 384 * 4);      // per-batch dp1 tgt-term bias
  float* h1     = (float*)alloc((size_t)MD * 384 * 4);      // 25.2 MB
  float* h2     = (float*)alloc((size_t)MD * 192 * 4);      // 12.6 MB
  float* sdec   = (float*)alloc((size_t)MD * 4);

  // converts
  {
    int n4 = MQ * CDIM / 4;
    k_convert4<<<dim3((n4 + 255)/256), dim3(256), 0, stream>>>((const float4*)x, (ushort4*)xb, n4);
  }
  {
    int n4 = 2304 * CDIM / 4;
    k_convert4<<<dim3((n4 + 255)/256), dim3(256), 0, stream>>>((const float4*)qkv_w, (ushort4*)qkv_wb, n4);
  }
  {
    int n4 = CDIM * CDIM / 4;
    k_convert4<<<dim3((n4 + 255)/256), dim3(256), 0, stream>>>((const float4*)proj_w, (ushort4*)proj_wb, n4);
  }
  k_tgt<<<dim3(B_), dim3(CDIM), 0, stream>>>(x, tgt);

  // qkv = x @ qkv_w.T + qkv_b  (bf16 out, scattered to head-major Q/K/V)
  k_gemm128<<<dim3(2304/128, (MQ + 127)/128), dim3(256), 0, stream>>>(xb, qkv_wb, qkv_b, qh, kh, vh,
                                                                      (float*)nullptr, MQ, 2304, CDIM, 0);
  // decision path (fp32):
  k_gemm_f32<<<dim3(384/64, 1), dim3(256), 0, stream>>>(tgt, nullptr, dp1_w + 768, 1536, dp1_b, tb,
                                                        B_, 384, CDIM, 0, 0, 0);
  k_gemm_f32<<<dim3(384/64, MD/128), dim3(256), 0, stream>>>(nullptr, x, dp1_w, 1536, tb, h1,
                                                             MD, 384, CDIM, 1, 1, 1);
  k_gemm_f32<<<dim3(192/64, MD/128), dim3(256), 0, stream>>>(h1, nullptr, dp2_w, 384, dp2_b, h2,
                                                             MD, 192, 384, 0, 1, 0);
  k_decision<<<dim3(MD/256), dim3(256), 0, stream>>>(h2, dp3_w, dp3_b, sdec);

  // attention (512 threads / 8 waves per block)
  k_attn<<<dim3(B_, NH), dim3(512), 0, stream>>>(qh, kh, vh, sdec, Obuf);

  // out = O @ proj_w.T + proj_b (fp32 out)
  k_gemm128<<<dim3(CDIM/128, (MP + 127)/128), dim3(256), 0, stream>>>(Obuf, proj_wb, proj_b,
                                                                      nullptr, nullptr, nullptr, out,
                                                                      MP, CDIM, CDIM, 1);
}

// Round 5
// 707.702 us; speedup vs baseline: 1.2136x; 1.1145x over previous
//
#include <hip/hip_runtime.h>
#include <cmath>

typedef unsigned short u16;
typedef unsigned int u32;
typedef __attribute__((ext_vector_type(8))) short short8;
typedef __attribute__((ext_vector_type(4))) float f32x4;

#define B_    64
#define NV    385
#define CDIM  768
#define NQ    321
#define SFL   256
#define NH    12
#define HD    64
#define MQ    (B_*NV)   /* 24640 */
#define MP    (B_*NQ)   /* 20544 */
#define MD    (B_*SFL)  /* 16384 */
#define SCALE_ 0.125f
#define EPS_   1e-6f

__device__ __forceinline__ u16 f2b(float f) {
  u32 x = __float_as_uint(f);
  return (u16)((x + 0x7FFFu + ((x >> 16) & 1u)) >> 16);
}
__device__ __forceinline__ float b2f(u16 h) {
  return __uint_as_float((u32)h << 16);
}

__device__ __forceinline__ void gload_lds16(const void* g, void* l) {
  __builtin_amdgcn_global_load_lds(
      (const __attribute__((address_space(1))) u32*)g,
      (__attribute__((address_space(3))) u32*)l,
      16, 0, 0);
}

// ---------------- fp32 -> bf16 convert (vectorized) ----------------
__global__ void k_convert4(const float4* __restrict__ in, ushort4* __restrict__ out, int n4) {
  int i = blockIdx.x * blockDim.x + threadIdx.x;
  if (i < n4) {
    float4 v = in[i];
    ushort4 o;
    o.x = f2b(v.x); o.y = f2b(v.y); o.z = f2b(v.z); o.w = f2b(v.w);
    out[i] = o;
  }
}

// ---------------- gather x search rows -> hi/lo bf16 split ----------------
__global__ void k_gather_split(const float* __restrict__ x, ushort4* __restrict__ hi,
                               ushort4* __restrict__ lo, int n4) {
  int idx = blockIdx.x * blockDim.x + threadIdx.x; // over MD*192 float4s
  if (idx < n4) {
    int m = idx / 192, c4 = idx - m*192;
    int b = m >> 8, s = m & 255;
    float4 v = *(const float4*)(x + ((size_t)(b*NV + 129 + s))*CDIM + c4*4);
    ushort4 h, l;
    h.x = f2b(v.x); l.x = f2b(v.x - b2f(h.x));
    h.y = f2b(v.y); l.y = f2b(v.y - b2f(h.y));
    h.z = f2b(v.z); l.z = f2b(v.z - b2f(h.z));
    h.w = f2b(v.w); l.w = f2b(v.w - b2f(h.w));
    hi[idx] = h; lo[idx] = l;
  }
}

// ---------------- weight hi/lo split (with optional zero row-padding) ----------------
__global__ void k_split_w(const float* __restrict__ W, int ldw, int rows, int colsDiv4,
                          int outRows, ushort4* __restrict__ hi, ushort4* __restrict__ lo) {
  int idx = blockIdx.x * blockDim.x + threadIdx.x;
  if (idx < outRows * colsDiv4) {
    int r = idx / colsDiv4, c4 = idx - r*colsDiv4;
    ushort4 h = {0,0,0,0}, l = {0,0,0,0};
    if (r < rows) {
      float4 v = *(const float4*)(W + (size_t)r*ldw + c4*4);
      h.x = f2b(v.x); l.x = f2b(v.x - b2f(h.x));
      h.y = f2b(v.y); l.y = f2b(v.y - b2f(h.y));
      h.z = f2b(v.z); l.z = f2b(v.z - b2f(h.z));
      h.w = f2b(v.w); l.w = f2b(v.w - b2f(h.w));
    }
    hi[idx] = h; lo[idx] = l;
  }
}

// ---------------- tgt_rep = mean over x[:, 65:129, :] ----------------
__global__ void k_tgt(const float* __restrict__ x, float* __restrict__ tgt) {
  int b = blockIdx.x, c = threadIdx.x; // block = 768 threads
  float s = 0.f;
  for (int j = 0; j < 64; ++j) s += x[((size_t)(b*NV + 65 + j))*CDIM + c];
  tgt[b*CDIM + c] = s * (1.f/64.f);
}

__device__ __forceinline__ float gelu_exact(float x) {
  return 0.5f * x * (1.f + erff(x * 0.70710678118654752f));
}

// ---------------- 128x128 bf16 MFMA GEMM, BK=64, XOR-swizzled LDS ----------------
// mode 0 -> qkv path: scatter bf16 C into head-major Qh/Kh/Vh [h][b][n][64]
// mode 1 -> f32 out (direct, used for proj)
__global__ __launch_bounds__(256) void k_gemm128(const u16* __restrict__ A, const u16* __restrict__ W,
                                                 const float* __restrict__ bias,
                                                 u16* __restrict__ Qh, u16* __restrict__ Kh, u16* __restrict__ Vh,
                                                 float* __restrict__ Cf,
                                                 int M, int N, int K, int mode) {
  __shared__ __align__(16) u16 sbuf[128*128];  // 32 KB: As=sbuf[0:8192), Ws=sbuf[8192:16384)
  u16* As = sbuf;
  u16* Ws = sbuf + 8192;
  int tid = threadIdx.x;
  int wave = tid >> 6, lane = tid & 63;
  int quad = lane >> 4, col = lane & 15;
  int m0 = blockIdx.y * 128, n0 = blockIdx.x * 128;

  const u16* pa[4];
  const u16* pb[4];
#pragma unroll
  for (int p = 0; p < 4; ++p) {
    int c = p*256 + tid;
    int row = c >> 3;
    int sg = (c & 7) ^ (row & 7);          // XOR swizzle (source-side)
    pa[p] = A + (size_t)min(m0 + row, M - 1) * K + sg*8;
    pb[p] = W + (size_t)(n0 + row) * K + sg*8;
  }

  int wm = (wave >> 1) * 64, wn = (wave & 1) * 64;
  f32x4 acc[4][4];
  f32x4 z4 = {0.f, 0.f, 0.f, 0.f};
#pragma unroll
  for (int i = 0; i < 4; ++i)
#pragma unroll
    for (int j = 0; j < 4; ++j) acc[i][j] = z4;

  for (int k0 = 0; k0 < K; k0 += 64) {
#pragma unroll
    for (int p = 0; p < 4; ++p) {
      gload_lds16(pa[p], &As[(p*256 + wave*64) * 8]);
      gload_lds16(pb[p], &Ws[(p*256 + wave*64) * 8]);
      pa[p] += 64; pb[p] += 64;
    }
    __syncthreads();

#pragma unroll
    for (int kk = 0; kk < 2; ++kk) {
      int sr = quad + kk*4;                // 16B chunk index within the 64-u16 row
      short8 af[4], bf[4];
#pragma unroll
      for (int i = 0; i < 4; ++i) {
        int row = wm + i*16 + col;
        af[i] = *(const short8*)&As[row*64 + ((sr ^ (row & 7)) * 8)];
      }
#pragma unroll
      for (int j = 0; j < 4; ++j) {
        int row = wn + j*16 + col;
        bf[j] = *(const short8*)&Ws[row*64 + ((sr ^ (row & 7)) * 8)];
      }
#pragma unroll
      for (int i = 0; i < 4; ++i)
#pragma unroll
        for (int j = 0; j < 4; ++j)
          acc[i][j] = __builtin_amdgcn_mfma_f32_16x16x32_bf16(af[i], bf[j], acc[i][j], 0, 0, 0);
    }
    __syncthreads();
  }

  if (mode == 0) {
    // stage C-tile (bf16) in sbuf[128][128], then scatter to head-major Q/K/V
#pragma unroll
    for (int j = 0; j < 4; ++j) {
      int cc = wn + j*16 + col;
      float bv = bias ? bias[n0 + cc] : 0.f;
#pragma unroll
      for (int i = 0; i < 4; ++i)
#pragma unroll
        for (int ii = 0; ii < 4; ++ii) {
          int row = wm + i*16 + quad*4 + ii;
          sbuf[row*128 + cc] = f2b(acc[i][j][ii] + bv);
        }
    }
    __syncthreads();
#pragma unroll
    for (int q = 0; q < 8; ++q) {
      int idx = q*256 + tid;
      int row = idx >> 4, c16 = idx & 15;
      int mg = m0 + row;
      if (mg < M) {
        int n = n0 + c16*8;
        int which = n / 768;               // 128-col tiles never straddle a 768 boundary
        int rem = n - which*768;
        int hh = rem >> 6, d0 = rem & 63;
        int bb = mg / NV, nn = mg - bb*NV;
        u16* dst = (which == 0) ? Qh : (which == 1) ? Kh : Vh;
        *(float4*)(dst + (((size_t)hh*B_ + bb)*NV + nn)*64 + d0) = *(const float4*)&sbuf[row*128 + c16*8];
      }
    }
  } else {
#pragma unroll
    for (int j = 0; j < 4; ++j) {
      int cc = n0 + wn + j*16 + col;
      float bv = bias ? bias[cc] : 0.f;
#pragma unroll
      for (int i = 0; i < 4; ++i) {
        int r = m0 + wm + i*16 + quad*4;
#pragma unroll
        for (int ii = 0; ii < 4; ++ii) {
          if (r + ii < M) Cf[(size_t)(r + ii) * N + cc] = acc[i][j][ii] + bv;
        }
      }
    }
  }
}

// ---------------- split-fp32 GEMM via 3x bf16 MFMA (decision path) ----------------
// C = (Ah+Al)@(Wh+Wl)^T ~= Ah@Wh + Ah@Wl + Al@Wh  (error ~2^-17 rel).
// geluF=1: v = gelu(acc + bias2[b][n]); emit hi/lo bf16 (Chi/Clo), N-strided.
// geluF=0: f32 out to Cf (stride N), bias[n] only for n<Nb (zero-padded cols).
__global__ __launch_bounds__(256) void k_gemm128s(const u16* __restrict__ Ah, const u16* __restrict__ Al,
                                                  const u16* __restrict__ Wh, const u16* __restrict__ Wl,
                                                  const float* __restrict__ bias, const float* __restrict__ bias2,
                                                  u16* __restrict__ Chi, u16* __restrict__ Clo,
                                                  float* __restrict__ Cf,
                                                  int M, int N, int K, int Nb, int geluF) {
  __shared__ __align__(16) u16 sb[4*8192];   // 64 KB: sAh, sAl, sWh, sWl
  u16* sAh = sb;
  u16* sAl = sb + 8192;
  u16* sWh = sb + 16384;
  u16* sWl = sb + 24576;
  int tid = threadIdx.x;
  int wave = tid >> 6, lane = tid & 63;
  int quad = lane >> 4, col = lane & 15;
  int m0 = blockIdx.y * 128, n0 = blockIdx.x * 128;

  const u16 *pah[4], *pal[4], *pbh[4], *pbl[4];
#pragma unroll
  for (int p = 0; p < 4; ++p) {
    int c = p*256 + tid;
    int row = c >> 3;
    int sg = (c & 7) ^ (row & 7);
    size_t ao = (size_t)min(m0 + row, M - 1) * K + sg*8;
    size_t bo = (size_t)(n0 + row) * K + sg*8;
    pah[p] = Ah + ao; pal[p] = Al + ao;
    pbh[p] = Wh + bo; pbl[p] = Wl + bo;
  }

  int wm = (wave >> 1) * 64, wn = (wave & 1) * 64;
  f32x4 acc[4][4];
  f32x4 z4 = {0.f, 0.f, 0.f, 0.f};
#pragma unroll
  for (int i = 0; i < 4; ++i)
#pragma unroll
    for (int j = 0; j < 4; ++j) acc[i][j] = z4;

  for (int k0 = 0; k0 < K; k0 += 64) {
#pragma unroll
    for (int p = 0; p < 4; ++p) {
      int dst = (p*256 + wave*64) * 8;
      gload_lds16(pah[p], &sAh[dst]);
      gload_lds16(pal[p], &sAl[dst]);
      gload_lds16(pbh[p], &sWh[dst]);
      gload_lds16(pbl[p], &sWl[dst]);
      pah[p] += 64; pal[p] += 64; pbh[p] += 64; pbl[p] += 64;
    }
    __syncthreads();

#pragma unroll
    for (int kk = 0; kk < 2; ++kk) {
      int sr = quad + kk*4;
      short8 ah[4], al[4], bh[4], bl[4];
#pragma unroll
      for (int i = 0; i < 4; ++i) {
        int row = wm + i*16 + col;
        int off = row*64 + ((sr ^ (row & 7)) * 8);
        ah[i] = *(const short8*)&sAh[off];
        al[i] = *(const short8*)&sAl[off];
      }
#pragma unroll
      for (int j = 0; j < 4; ++j) {
        int row = wn + j*16 + col;
        int off = row*64 + ((sr ^ (row & 7)) * 8);
        bh[j] = *(const short8*)&sWh[off];
        bl[j] = *(const short8*)&sWl[off];
      }
#pragma unroll
      for (int i = 0; i < 4; ++i)
#pragma unroll
        for (int j = 0; j < 4; ++j) {
          acc[i][j] = __builtin_amdgcn_mfma_f32_16x16x32_bf16(ah[i], bh[j], acc[i][j], 0, 0, 0);
          acc[i][j] = __builtin_amdgcn_mfma_f32_16x16x32_bf16(ah[i], bl[j], acc[i][j], 0, 0, 0);
          acc[i][j] = __builtin_amdgcn_mfma_f32_16x16x32_bf16(al[i], bh[j], acc[i][j], 0, 0, 0);
        }
    }
    __syncthreads();
  }

  if (geluF) {
    // gelu + hi/lo bf16 emit, LDS-staged for coalesced stores
#pragma unroll
    for (int j = 0; j < 4; ++j) {
      int cc = wn + j*16 + col;
      float bv = bias ? bias[n0 + cc] : 0.f;
#pragma unroll
      for (int i = 0; i < 4; ++i)
#pragma unroll
        for (int ii = 0; ii < 4; ++ii) {
          int row = wm + i*16 + quad*4 + ii;
          int mg = m0 + row;
          float v = acc[i][j][ii] + bv;
          if (bias2) v += bias2[(size_t)(mg >> 8) * N + n0 + cc];
          v = gelu_exact(v);
          u16 hi = f2b(v);
          sb[row*128 + cc] = hi;
          sb[16384 + row*128 + cc] = f2b(v - b2f(hi));
        }
    }
    __syncthreads();
#pragma unroll
    for (int q = 0; q < 8; ++q) {
      int idx = q*256 + tid;
      int row = idx >> 4, c16 = idx & 15;
      int mg = m0 + row;
      if (mg < M) {
        *(float4*)(Chi + (size_t)mg * N + n0 + c16*8) = *(const float4*)&sb[row*128 + c16*8];
        *(float4*)(Clo + (size_t)mg * N + n0 + c16*8) = *(const float4*)&sb[16384 + row*128 + c16*8];
      }
    }
  } else {
#pragma unroll
    for (int j = 0; j < 4; ++j) {
      int ccg = n0 + wn + j*16 + col;
      float bv = (bias && ccg < Nb) ? bias[ccg] : 0.f;
#pragma unroll
      for (int i = 0; i < 4; ++i) {
        int r = m0 + wm + i*16 + quad*4;
#pragma unroll
        for (int ii = 0; ii < 4; ++ii) {
          if (r + ii < M) Cf[(size_t)(r + ii) * N + ccg] = acc[i][j][ii] + bv;
        }
      }
    }
  }
}

// ---------------- fp32 GEMM (kept for tiny tb pass) ----------------
__global__ __launch_bounds__(256) void k_gemm_f32(const float* __restrict__ A,
                                                  const float* __restrict__ x,
                                                  const float* __restrict__ W, int ldw,
                                                  const float* __restrict__ bias,
                                                  float* __restrict__ C, int M, int N, int K,
                                                  int gather, int gelu, int bias2d) {
  __shared__ __align__(16) float As[16][132];
  __shared__ __align__(16) float Ws[16][68];
  int tid = threadIdx.x;
  int tx = tid & 15, ty = tid >> 4;
  int n0 = blockIdx.x * 64, m0 = blockIdx.y * 128;
  float acc[8][4] = {};

  for (int k0 = 0; k0 < K; k0 += 16) {
#pragma unroll
    for (int p = 0; p < 2; ++p) {
      int f = p * 256 + tid;
      int row = f >> 2, kc = (f & 3) * 4;
      float4 v;
      if (gather) {
        int m = m0 + row;
        int b = m >> 8, s2 = m & 255;
        v = *(const float4*)(x + ((size_t)(b*NV + 129 + s2))*CDIM + k0 + kc);
      } else {
        int m = min(m0 + row, M - 1);
        v = *(const float4*)(A + (size_t)m * K + k0 + kc);
      }
      As[kc+0][row] = v.x; As[kc+1][row] = v.y; As[kc+2][row] = v.z; As[kc+3][row] = v.w;
    }
    {
      int row = tid >> 2, kc = (tid & 3) * 4;
      float4 wv = *(const float4*)(W + (size_t)(n0 + row) * ldw + k0 + kc);
      Ws[kc+0][row] = wv.x; Ws[kc+1][row] = wv.y; Ws[kc+2][row] = wv.z; Ws[kc+3][row] = wv.w;
    }
    __syncthreads();
#pragma unroll
    for (int k2 = 0; k2 < 16; ++k2) {
      float4 a0 = *(const float4*)&As[k2][ty*8];
      float4 a1 = *(const float4*)&As[k2][ty*8 + 4];
      float4 wv = *(const float4*)&Ws[k2][tx*4];
      float a_[8] = {a0.x, a0.y, a0.z, a0.w, a1.x, a1.y, a1.z, a1.w};
      float w_[4] = {wv.x, wv.y, wv.z, wv.w};
#pragma unroll
      for (int i = 0; i < 8; ++i)
#pragma unroll
        for (int j = 0; j < 4; ++j) acc[i][j] += a_[i] * w_[j];
    }
    __syncthreads();
  }
#pragma unroll
  for (int i = 0; i < 8; ++i) {
    int r = m0 + ty*8 + i;
    if (r < M) {
      float4 o;
      float* op = (float*)&o;
#pragma unroll
      for (int j = 0; j < 4; ++j) {
        int n = n0 + tx*4 + j;
        float bv = bias2d ? bias[(size_t)(r >> 8) * N + n] : bias[n];
        float v = acc[i][j] + bv;
        op[j] = gelu ? gelu_exact(v) : v;
      }
      *(float4*)(C + (size_t)r * N + n0 + tx*4) = o;
    }
  }
}

// ---------------- decision: argmax of (gelu(h2f) @ dp3_w.T + dp3_b), fp32 ----------------
__global__ void k_decision(const float* __restrict__ h2f, const float* __restrict__ w3,
                           const float* __restrict__ b3, float* __restrict__ sdec) {
  int r = blockIdx.x * blockDim.x + threadIdx.x; // 16384 rows
  const float* hp = h2f + (size_t)r * 256;       // h2f stride 256 (pre-gelu)
  float l0 = b3[0], l1 = b3[1];
  for (int k = 0; k < 192; ++k) {
    float h = gelu_exact(hp[k]);
    l0 += h * w3[k]; l1 += h * w3[192 + k];
  }
  sdec[r] = (l1 > l0) ? 1.f : 0.f; // jnp.argmax ties -> 0
}

// ---------------- attention v5: swapped QK^T, shfl broadcasts ----------------
__global__ __launch_bounds__(512, 4) void k_attn(const u16* __restrict__ Qh, const u16* __restrict__ Kh,
                                                 const u16* __restrict__ Vh, const float* __restrict__ sdec,
                                                 u16* __restrict__ O) {
  __shared__ __align__(16) u16 vsT[64*424];    // V^T swizzled: (d,n) at d*424 + cs*8 + (n&7)
  __shared__ __align__(16) u16 pst[8][16][72]; // per-wave P staging: [q][key64], stride 72
  __shared__ float sd[256];
  __shared__ __align__(16) float sdm[416];     // template-row mask table over keys
  __shared__ float vsum[64];
  float* vpart = (float*)pst;                  // prologue alias (8*64 floats)

  int b = blockIdx.x, h = blockIdx.y;
  int tid = threadIdx.x;
  int wave = tid >> 6, lane = tid & 63;
  int quad = lane >> 4, col = lane & 15;

  size_t base = ((size_t)(h*B_ + b))*NV*64;
  const u16* Qb = Qh + base;
  const u16* Kb = Kh + base;
  const u16* Vb = Vh + base;

  if (tid < 256) sd[tid] = sdec[b*SFL + tid];
  for (int k = tid; k < 416; k += 512)
    sdm[k] = (k < 129) ? 1.f : ((k <= 384) ? sdec[b*SFL + k - 129] : 0.f);

  for (int i = tid; i < 64*39; i += 512) {
    int d = i / 39, n = 385 + (i - d*39);
    vsT[d*424 + n] = 0;
  }
  for (int idx = tid; idx < NV*8; idx += 512) {
    int n = idx >> 3, seg = idx & 7;
    short8 v = *(const short8*)(Vb + (size_t)n*64 + seg*8);
    int c = n >> 3;
    int cs = (c < 48) ? ((c & ~7) | ((c + seg) & 7)) : c;
    int b2 = cs*8 + (n & 7);
#pragma unroll
    for (int j = 0; j < 8; ++j)
      vsT[(seg*8 + j)*424 + b2] = ((const u16*)&v)[j];
  }
  __syncthreads();

  {
    int d = tid & 63, part = tid >> 6;
    int n_lo = part*49, n_hi = min(n_lo + 49, 385);
    float s = 0.f;
    for (int n = n_lo; n < n_hi; ++n) {
      int c = n >> 3;
      int cs = (c < 48) ? ((c & ~7) | ((c + (d >> 3)) & 7)) : c;
      s += __uint_as_float((u32)vsT[d*424 + cs*8 + (n & 7)] << 16);
    }
    vpart[part*64 + d] = s;
  }
  __syncthreads();
  if (tid < 64) {
    float s = 0.f;
#pragma unroll
    for (int p = 0; p < 8; ++p) s += vpart[p*64 + tid];
    vsum[tid] = s;
  }
  __syncthreads();

  const f32x4 z4 = {0.f, 0.f, 0.f, 0.f};
  float vsn[4];
#pragma unroll
  for (int nt = 0; nt < 4; ++nt) vsn[nt] = vsum[nt*16 + col];

  for (int t = wave; t < 21; t += 8) {
    int qn_lane = t*16 + col;
    int pos = (qn_lane == 0) ? 0 : (min(qn_lane, 320) + 64);
    const u16* qp = Qb + (size_t)pos*64 + quad*8;
    short8 aq0 = *(const short8*)(qp);
    short8 aq1 = *(const short8*)(qp + 32);

    bool isTpl = (qn_lane >= 1 && qn_lane <= 64);
    bool isSearch = (qn_lane >= 65);
    float sdq = isSearch ? sd[min(qn_lane - 65, 255)] : 1.f;

    float m_ = -1e30f, l_ = 0.f;
    f32x4 oc[4];
#pragma unroll
    for (int nt = 0; nt < 4; ++nt) oc[nt] = z4;

    for (int ch = 0; ch < 6; ++ch) {
      int key0c = ch*64;
      f32x4 acc4[4];
#pragma unroll
      for (int j = 0; j < 4; ++j) acc4[j] = z4;
#pragma unroll
      for (int j = 0; j < 4; ++j) {
        const u16* kp = Kb + (size_t)(key0c + j*16 + col)*64;
        short8 k0 = *(const short8*)(kp + quad*8);
        short8 k1 = *(const short8*)(kp + 32 + quad*8);
        acc4[j] = __builtin_amdgcn_mfma_f32_16x16x32_bf16(k0, aq0, acc4[j], 0, 0, 0);
        acc4[j] = __builtin_amdgcn_mfma_f32_16x16x32_bf16(k1, aq1, acc4[j], 0, 0, 0);
      }
      float cm = acc4[0][0];
#pragma unroll
      for (int j = 0; j < 4; ++j)
#pragma unroll
        for (int r = 0; r < 4; ++r)
          if (j || r) cm = fmaxf(cm, acc4[j][r]);
      cm = fmaxf(cm, __shfl_xor(cm, 16, 64));
      cm = fmaxf(cm, __shfl_xor(cm, 32, 64));
      float mn = fmaxf(m_, cm * SCALE_);
      float rnew = __expf(m_ - mn);
      m_ = mn;
      float rb[4];
#pragma unroll
      for (int r = 0; r < 4; ++r) rb[r] = __shfl(rnew, quad*4 + r, 64);
#pragma unroll
      for (int nt = 0; nt < 4; ++nt) {
        oc[nt][0] *= rb[0]; oc[nt][1] *= rb[1]; oc[nt][2] *= rb[2]; oc[nt][3] *= rb[3];
      }

      float ssum = 0.f;
#pragma unroll
      for (int j = 0; j < 4; ++j) {
        int key0 = key0c + j*16;
        float4 tm = make_float4(1.f, 1.f, 1.f, 1.f);
        if (isTpl) tm = *(const float4*)&sdm[key0 + quad*4];
        float a[4];
        const float* tmp = (const float*)&tm;
#pragma unroll
        for (int r = 0; r < 4; ++r) {
          int key = key0 + quad*4 + r;
          float msk = isTpl ? tmp[r]
                            : ((isSearch && key >= 1 && key <= 128) ? sdq : 1.f);
          a[r] = __expf(fmaf(acc4[j][r], SCALE_, -mn)) * msk;
          ssum += a[r];
        }
        uint2 pk;
        pk.x = (u32)f2b(a[0]) | ((u32)f2b(a[1]) << 16);
        pk.y = (u32)f2b(a[2]) | ((u32)f2b(a[3]) << 16);
        *(uint2*)&pst[wave][col][j*16 + quad*4] = pk;
      }
      ssum += __shfl_xor(ssum, 16, 64);
      ssum += __shfl_xor(ssum, 32, 64);
      l_ = l_ * rnew + ssum;

      asm volatile("" ::: "memory");
#pragma unroll
      for (int st = 0; st < 2; ++st) {
        short8 pa = *(const short8*)&pst[wave][col][st*32 + quad*8];
        int step = ch*2 + st;
#pragma unroll
        for (int nt = 0; nt < 4; ++nt) {
          int d = nt*16 + col;
          int c = step*4 + quad;
          int cs = (c & ~7) | ((c + (d >> 3)) & 7);
          short8 bv = *(const short8*)&vsT[d*424 + cs*8];
          oc[nt] = __builtin_amdgcn_mfma_f32_16x16x32_bf16(pa, bv, oc[nt], 0, 0, 0);
        }
      }
    }

    {
      const u16* kp = Kb + (size_t)384*64;
      short8 k0 = *(const short8*)(kp + quad*8);
      short8 k1 = *(const short8*)(kp + 32 + quad*8);
      f32x4 accE = z4;
      accE = __builtin_amdgcn_mfma_f32_16x16x32_bf16(k0, aq0, accE, 0, 0, 0);
      accE = __builtin_amdgcn_mfma_f32_16x16x32_bf16(k1, aq1, accE, 0, 0, 0);
      float cm = (quad == 0) ? accE[0] : -1e30f;
      cm = fmaxf(cm, __shfl_xor(cm, 16, 64));
      cm = fmaxf(cm, __shfl_xor(cm, 32, 64));
      float mn = fmaxf(m_, cm * SCALE_);
      float rnew = __expf(m_ - mn);
      m_ = mn;
      float rb[4];
#pragma unroll
      for (int r = 0; r < 4; ++r) rb[r] = __shfl(rnew, quad*4 + r, 64);
#pragma unroll
      for (int nt = 0; nt < 4; ++nt) {
        oc[nt][0] *= rb[0]; oc[nt][1] *= rb[1]; oc[nt][2] *= rb[2]; oc[nt][3] *= rb[3];
      }
      float mskE = isTpl ? sdm[384] : 1.f;
      float aE = (quad == 0) ? __expf(fmaf(accE[0], SCALE_, -mn)) * mskE : 0.f;
      float ssum = aE;
      ssum += __shfl_xor(ssum, 16, 64);
      ssum += __shfl_xor(ssum, 32, 64);
      l_ = l_ * rnew + ssum;

      uint2 pk;
      pk.x = (quad == 0) ? (u32)f2b(aE) : 0u;
      pk.y = 0u;
      *(uint2*)&pst[wave][col][quad*4] = pk;
      *(uint2*)&pst[wave][col][16 + quad*4] = make_uint2(0u, 0u);
      asm volatile("" ::: "memory");
      short8 pa = *(const short8*)&pst[wave][col][quad*8];
#pragma unroll
      for (int nt = 0; nt < 4; ++nt) {
        int d = nt*16 + col;
        short8 bv = *(const short8*)&vsT[d*424 + (48 + quad)*8];
        oc[nt] = __builtin_amdgcn_mfma_f32_16x16x32_bf16(pa, bv, oc[nt], 0, 0, 0);
      }
    }

    float lb[4];
#pragma unroll
    for (int r = 0; r < 4; ++r) lb[r] = __shfl(l_, quad*4 + r, 64);
    const float epsn = EPS_ / 321.f;
#pragma unroll
    for (int r = 0; r < 4; ++r) {
      float invv = 1.f / (lb[r] + EPS_);
      int qn = t*16 + quad*4 + r;
      if (qn <= 320) {
#pragma unroll
        for (int nt = 0; nt < 4; ++nt) {
          float val = (oc[nt][r] + epsn * vsn[nt]) * invv;
          O[((size_t)(b*NQ + qn))*CDIM + h*HD + nt*16 + col] = f2b(val);
        }
      }
    }
  }
}

extern "C" void kernel_launch(void* const* d_in, const int* in_sizes, int n_in,
                              void* d_out, int out_size, void* d_ws, size_t ws_size,
                              hipStream_t stream) {
  const float* x      = (const float*)d_in[0];
  const float* qkv_w  = (const float*)d_in[2];
  const float* qkv_b  = (const float*)d_in[3];
  const float* proj_w = (const float*)d_in[4];
  const float* proj_b = (const float*)d_in[5];
  const float* dp1_w  = (const float*)d_in[6];
  const float* dp1_b  = (const float*)d_in[7];
  const float* dp2_w  = (const float*)d_in[8];
  const float* dp2_b  = (const float*)d_in[9];
  const float* dp3_w  = (const float*)d_in[10];
  const float* dp3_b  = (const float*)d_in[11];
  float* out = (float*)d_out;

  char* ws = (char*)d_ws;
  size_t off = 0;
  auto alloc = [&](size_t bytes) -> void* {
    void* p = ws + off;
    off += (bytes + 255) & ~(size_t)255;
    return p;
  };
  u16*  xb      = (u16*)alloc((size_t)MQ * CDIM * 2);       // 37.8 MB
  u16*  qkv_wb  = (u16*)alloc((size_t)2304 * CDIM * 2);     // 3.5 MB
  u16*  proj_wb = (u16*)alloc((size_t)CDIM * CDIM * 2);     // 1.2 MB
  u16*  qh      = (u16*)alloc((size_t)NH * B_ * NV * 64 * 2); // 37.8 MB
  u16*  kh      = (u16*)alloc((size_t)NH * B_ * NV * 64 * 2); // 37.8 MB
  u16*  vh      = (u16*)alloc((size_t)NH * B_ * NV * 64 * 2); // 37.8 MB
  u16*  Obuf    = (u16*)alloc((size_t)MP * CDIM * 2);       // 31.6 MB
  float* tgt    = (float*)alloc((size_t)B_ * CDIM * 4);
  float* tb     = (float*)alloc((size_t)B_ * 384 * 4);      // dp1 tgt-term (incl dp1_b)
  u16*  xsh     = (u16*)alloc((size_t)MD * CDIM * 2);       // 25.2 MB (x search rows, hi)
  u16*  xsl     = (u16*)alloc((size_t)MD * CDIM * 2);       // 25.2 MB (lo)
  u16*  w1h     = (u16*)alloc((size_t)384 * CDIM * 2);
  u16*  w1l     = (u16*)alloc((size_t)384 * CDIM * 2);
  u16*  w2h     = (u16*)alloc((size_t)256 * 384 * 2);
  u16*  w2l     = (u16*)alloc((size_t)256 * 384 * 2);
  u16*  h1h     = (u16*)alloc((size_t)MD * 384 * 2);        // 12.6 MB
  u16*  h1l     = (u16*)alloc((size_t)MD * 384 * 2);        // 12.6 MB
  float* h2f    = (float*)alloc((size_t)MD * 256 * 4);      // 16.8 MB (pre-gelu, padded)
  float* sdec   = (float*)alloc((size_t)MD * 4);

  // converts
  {
    int n4 = MQ * CDIM / 4;
    k_convert4<<<dim3((n4 + 255)/256), dim3(256), 0, stream>>>((const float4*)x, (ushort4*)xb, n4);
  }
  {
    int n4 = 2304 * CDIM / 4;
    k_convert4<<<dim3((n4 + 255)/256), dim3(256), 0, stream>>>((const float4*)qkv_w, (ushort4*)qkv_wb, n4);
  }
  {
    int n4 = CDIM * CDIM / 4;
    k_convert4<<<dim3((n4 + 255)/256), dim3(256), 0, stream>>>((const float4*)proj_w, (ushort4*)proj_wb, n4);
  }
  k_tgt<<<dim3(B_), dim3(CDIM), 0, stream>>>(x, tgt);

  // decision-path splits
  {
    int n4 = MD * 192;
    k_gather_split<<<dim3((n4 + 255)/256), dim3(256), 0, stream>>>(x, (ushort4*)xsh, (ushort4*)xsl, n4);
  }
  {
    int n4 = 384 * 192;
    k_split_w<<<dim3((n4 + 255)/256), dim3(256), 0, stream>>>(dp1_w, 1536, 384, 192, 384,
                                                              (ushort4*)w1h, (ushort4*)w1l);
  }
  {
    int n4 = 256 * 96;
    k_split_w<<<dim3((n4 + 255)/256), dim3(256), 0, stream>>>(dp2_w, 384, 192, 96, 256,
                                                              (ushort4*)w2h, (ushort4*)w2l);
  }

  // qkv = x @ qkv_w.T + qkv_b  (bf16 out, scattered to head-major Q/K/V)
  k_gemm128<<<dim3(2304/128, (MQ + 127)/128), dim3(256), 0, stream>>>(xb, qkv_wb, qkv_b, qh, kh, vh,
                                                                      (float*)nullptr, MQ, 2304, CDIM, 0);
  // tb = tgt @ dp1_w[:,768:].T + dp1_b  (tiny, fp32)
  k_gemm_f32<<<dim3(384/64, 1), dim3(256), 0, stream>>>(tgt, nullptr, dp1_w + 768, 1536, dp1_b, tb,
                                                        B_, 384, CDIM, 0, 0, 0);
  // dp1: h1 = gelu(Xs @ W1a.T + tb), split-fp32 via 3x bf16 MFMA, emits h1 hi/lo
  k_gemm128s<<<dim3(384/128, MD/128), dim3(256), 0, stream>>>(xsh, xsl, w1h, w1l,
                                                              nullptr, tb, h1h, h1l, nullptr,
                                                              MD, 384, CDIM, 384, 1);
  // dp2: h2f = h1 @ W2.T + b2 (pre-gelu, f32, N padded to 256)
  k_gemm128s<<<dim3(256/128, MD/128), dim3(256), 0, stream>>>(h1h, h1l, w2h, w2l,
                                                              dp2_b, nullptr, nullptr, nullptr, h2f,
                                                              MD, 256, 384, 192, 0);
  k_decision<<<dim3(MD/256), dim3(256), 0, stream>>>(h2f, dp3_w, dp3_b, sdec);

  // attention (512 threads / 8 waves per block)
  k_attn<<<dim3(B_, NH), dim3(512), 0, stream>>>(qh, kh, vh, sdec, Obuf);

  // out = O @ proj_w.T + proj_b (fp32 out)
  k_gemm128<<<dim3(CDIM/128, (MP + 127)/128), dim3(256), 0, stream>>>(Obuf, proj_wb, proj_b,
                                                                      nullptr, nullptr, nullptr, out,
                                                                      MP, CDIM, CDIM, 1);
}

// Round 7
// 599.495 us; speedup vs baseline: 1.4327x; 1.1805x over previous
//
#include <hip/hip_runtime.h>
#include <cmath>

typedef unsigned short u16;
typedef unsigned int u32;
typedef __attribute__((ext_vector_type(8))) short short8;
typedef __attribute__((ext_vector_type(4))) float f32x4;

#define B_    64
#define NV    385
#define CDIM  768
#define NQ    321
#define SFL   256
#define NH    12
#define HD    64
#define MQ    (B_*NV)   /* 24640 */
#define MP    (B_*NQ)   /* 20544 */
#define MD    (B_*SFL)  /* 16384 */
#define SCALE_ 0.125f
#define EPS_   1e-6f

__device__ __forceinline__ u16 f2b(float f) {
  u32 x = __float_as_uint(f);
  return (u16)((x + 0x7FFFu + ((x >> 16) & 1u)) >> 16);
}
__device__ __forceinline__ float b2f(u16 h) {
  return __uint_as_float((u32)h << 16);
}

__device__ __forceinline__ void gload_lds16(const void* g, void* l) {
  __builtin_amdgcn_global_load_lds(
      (const __attribute__((address_space(1))) u32*)g,
      (__attribute__((address_space(3))) u32*)l,
      16, 0, 0);
}

// bijective XCD swizzle (m204): contiguous logical blocks -> one XCD
__device__ __forceinline__ int xcd_swz(int lin, int nwg) {
  int xcd = lin & 7, idx = lin >> 3;
  int q = nwg >> 3, r = nwg & 7;
  int base = (xcd < r) ? xcd * (q + 1) : r * (q + 1) + (xcd - r) * q;
  return base + idx;
}

__device__ __forceinline__ float gelu_exact(float x) {
  return 0.5f * x * (1.f + erff(x * 0.70710678118654752f));
}

// ---------------- fused x prep: bf16 convert + search-row hi/lo split ----------------
__global__ void k_prep_x(const float* __restrict__ x, ushort4* __restrict__ xb,
                         ushort4* __restrict__ xsh, ushort4* __restrict__ xsl) {
  int row = blockIdx.x;            // 24640 rows
  int tid = threadIdx.x;           // 192 threads (float4 per thread)
  float4 v = ((const float4*)x)[(size_t)row*192 + tid];
  ushort4 h;
  h.x = f2b(v.x); h.y = f2b(v.y); h.z = f2b(v.z); h.w = f2b(v.w);
  xb[(size_t)row*192 + tid] = h;
  int b = row / NV, n = row - b*NV;
  if (n >= 129) {
    ushort4 l;
    l.x = f2b(v.x - b2f(h.x)); l.y = f2b(v.y - b2f(h.y));
    l.z = f2b(v.z - b2f(h.z)); l.w = f2b(v.w - b2f(h.w));
    size_t s = (size_t)(b*256 + n - 129)*192 + tid;
    xsh[s] = h; xsl[s] = l;
  }
}

// ---------------- fused weight prep: qkv/proj converts + dp1/dp2 hi-lo splits ----------------
#define PR0 442368              /* 2304*192: qkv_w */
#define PR1 (PR0 + 147456)      /* 768*192: proj_w */
#define PR2 (PR1 + 73728)       /* 384*192: dp1_w cols 0..767 */
#define PR3 (PR2 + 24576)       /* 256*96: dp2_w padded */
__global__ void k_prep_w(const float* __restrict__ qkv_w, const float* __restrict__ proj_w,
                         const float* __restrict__ dp1_w, const float* __restrict__ dp2_w,
                         ushort4* __restrict__ qkv_wb, ushort4* __restrict__ proj_wb,
                         ushort4* __restrict__ w1h, ushort4* __restrict__ w1l,
                         ushort4* __restrict__ w2h, ushort4* __restrict__ w2l) {
  int i = blockIdx.x * 256 + threadIdx.x;
  if (i < PR0) {
    float4 v = ((const float4*)qkv_w)[i];
    ushort4 h; h.x = f2b(v.x); h.y = f2b(v.y); h.z = f2b(v.z); h.w = f2b(v.w);
    qkv_wb[i] = h;
  } else if (i < PR1) {
    int j = i - PR0;
    float4 v = ((const float4*)proj_w)[j];
    ushort4 h; h.x = f2b(v.x); h.y = f2b(v.y); h.z = f2b(v.z); h.w = f2b(v.w);
    proj_wb[j] = h;
  } else if (i < PR2) {
    int j = i - PR1;
    int r = j / 192, c4 = j - r*192;
    float4 v = *(const float4*)(dp1_w + (size_t)r*1536 + c4*4);
    ushort4 h, l;
    h.x = f2b(v.x); l.x = f2b(v.x - b2f(h.x));
    h.y = f2b(v.y); l.y = f2b(v.y - b2f(h.y));
    h.z = f2b(v.z); l.z = f2b(v.z - b2f(h.z));
    h.w = f2b(v.w); l.w = f2b(v.w - b2f(h.w));
    w1h[j] = h; w1l[j] = l;
  } else if (i < PR3) {
    int j = i - PR2;
    int r = j / 96, c4 = j - r*96;
    ushort4 h = {0,0,0,0}, l = {0,0,0,0};
    if (r < 192) {
      float4 v = *(const float4*)(dp2_w + (size_t)r*384 + c4*4);
      h.x = f2b(v.x); l.x = f2b(v.x - b2f(h.x));
      h.y = f2b(v.y); l.y = f2b(v.y - b2f(h.y));
      h.z = f2b(v.z); l.z = f2b(v.z - b2f(h.z));
      h.w = f2b(v.w); l.w = f2b(v.w - b2f(h.w));
    }
    w2h[j] = h; w2l[j] = l;
  }
}

// ---------------- tgt_rep = mean over x[:, 65:129, :] ----------------
__global__ void k_tgt(const float* __restrict__ x, float* __restrict__ tgt) {
  int b = blockIdx.x, c = threadIdx.x; // block = 768 threads
  float s = 0.f;
  for (int j = 0; j < 64; ++j) s += x[((size_t)(b*NV + 65 + j))*CDIM + c];
  tgt[b*CDIM + c] = s * (1.f/64.f);
}

// ---------------- tb = tgt @ dp1_w[:,768:].T + dp1_b  (64x384x768, block per batch) ----------------
__global__ __launch_bounds__(256) void k_tb(const float* __restrict__ tgt, const float* __restrict__ dp1_w,
                                            const float* __restrict__ dp1_b, float* __restrict__ tb) {
  __shared__ float tg[768];
  int b = blockIdx.x, tid = threadIdx.x;
  for (int i = tid; i < 768; i += 256) tg[i] = tgt[b*768 + i];
  __syncthreads();
  for (int n = tid; n < 384; n += 256) {
    const float* w = dp1_w + (size_t)n*1536 + 768;
    float s = dp1_b[n];
    for (int k = 0; k < 768; k += 4) {
      float4 wv = *(const float4*)(w + k);
      s += tg[k]*wv.x + tg[k+1]*wv.y + tg[k+2]*wv.z + tg[k+3]*wv.w;
    }
    tb[b*384 + n] = s;
  }
}

// ---------------- 128x128 bf16 MFMA GEMM, BK=64, XOR-swizzled LDS, XCD-swizzled grid ----------------
// mode 0 -> qkv path: scatter bf16 C into head-major Qh/Kh/Vh [h][b][n][64]
// mode 1 -> f32 out (direct, used for proj)
__global__ __launch_bounds__(256) void k_gemm128(const u16* __restrict__ A, const u16* __restrict__ W,
                                                 const float* __restrict__ bias,
                                                 u16* __restrict__ Qh, u16* __restrict__ Kh, u16* __restrict__ Vh,
                                                 float* __restrict__ Cf,
                                                 int M, int N, int K, int mode) {
  __shared__ __align__(16) u16 sbuf[128*128];  // 32 KB: As=sbuf[0:8192), Ws=sbuf[8192:16384)
  u16* As = sbuf;
  u16* Ws = sbuf + 8192;
  int tid = threadIdx.x;
  int wave = tid >> 6, lane = tid & 63;
  int quad = lane >> 4, col = lane & 15;
  // XCD-aware bijective remap (T1): consecutive logical blocks (same A-panel) on one XCD
  int gx = gridDim.x;
  int lin = blockIdx.y * gx + blockIdx.x;
  int s = xcd_swz(lin, gx * gridDim.y);
  int bx = s % gx, by = s / gx;
  int m0 = by * 128, n0 = bx * 128;

  const u16* pa[4];
  const u16* pb[4];
#pragma unroll
  for (int p = 0; p < 4; ++p) {
    int c = p*256 + tid;
    int row = c >> 3;
    int sg = (c & 7) ^ (row & 7);          // XOR swizzle (source-side)
    pa[p] = A + (size_t)min(m0 + row, M - 1) * K + sg*8;
    pb[p] = W + (size_t)(n0 + row) * K + sg*8;
  }

  int wm = (wave >> 1) * 64, wn = (wave & 1) * 64;
  f32x4 acc[4][4];
  f32x4 z4 = {0.f, 0.f, 0.f, 0.f};
#pragma unroll
  for (int i = 0; i < 4; ++i)
#pragma unroll
    for (int j = 0; j < 4; ++j) acc[i][j] = z4;

  for (int k0 = 0; k0 < K; k0 += 64) {
#pragma unroll
    for (int p = 0; p < 4; ++p) {
      gload_lds16(pa[p], &As[(p*256 + wave*64) * 8]);
      gload_lds16(pb[p], &Ws[(p*256 + wave*64) * 8]);
      pa[p] += 64; pb[p] += 64;
    }
    __syncthreads();

#pragma unroll
    for (int kk = 0; kk < 2; ++kk) {
      int sr = quad + kk*4;                // 16B chunk index within the 64-u16 row
      short8 af[4], bf[4];
#pragma unroll
      for (int i = 0; i < 4; ++i) {
        int row = wm + i*16 + col;
        af[i] = *(const short8*)&As[row*64 + ((sr ^ (row & 7)) * 8)];
      }
#pragma unroll
      for (int j = 0; j < 4; ++j) {
        int row = wn + j*16 + col;
        bf[j] = *(const short8*)&Ws[row*64 + ((sr ^ (row & 7)) * 8)];
      }
#pragma unroll
      for (int i = 0; i < 4; ++i)
#pragma unroll
        for (int j = 0; j < 4; ++j)
          acc[i][j] = __builtin_amdgcn_mfma_f32_16x16x32_bf16(af[i], bf[j], acc[i][j], 0, 0, 0);
    }
    __syncthreads();
  }

  if (mode == 0) {
    // stage C-tile (bf16) in sbuf[128][128], then scatter to head-major Q/K/V
#pragma unroll
    for (int j = 0; j < 4; ++j) {
      int cc = wn + j*16 + col;
      float bv = bias ? bias[n0 + cc] : 0.f;
#pragma unroll
      for (int i = 0; i < 4; ++i)
#pragma unroll
        for (int ii = 0; ii < 4; ++ii) {
          int row = wm + i*16 + quad*4 + ii;
          sbuf[row*128 + cc] = f2b(acc[i][j][ii] + bv);
        }
    }
    __syncthreads();
#pragma unroll
    for (int q = 0; q < 8; ++q) {
      int idx = q*256 + tid;
      int row = idx >> 4, c16 = idx & 15;
      int mg = m0 + row;
      if (mg < M) {
        int n = n0 + c16*8;
        int which = n / 768;               // 128-col tiles never straddle a 768 boundary
        int rem = n - which*768;
        int hh = rem >> 6, d0 = rem & 63;
        int bb = mg / NV, nn = mg - bb*NV;
        u16* dst = (which == 0) ? Qh : (which == 1) ? Kh : Vh;
        *(float4*)(dst + (((size_t)hh*B_ + bb)*NV + nn)*64 + d0) = *(const float4*)&sbuf[row*128 + c16*8];
      }
    }
  } else {
#pragma unroll
    for (int j = 0; j < 4; ++j) {
      int cc = n0 + wn + j*16 + col;
      float bv = bias ? bias[cc] : 0.f;
#pragma unroll
      for (int i = 0; i < 4; ++i) {
        int r = m0 + wm + i*16 + quad*4;
#pragma unroll
        for (int ii = 0; ii < 4; ++ii) {
          if (r + ii < M) Cf[(size_t)(r + ii) * N + cc] = acc[i][j][ii] + bv;
        }
      }
    }
  }
}

// ---------------- split-fp32 GEMM via 3x bf16 MFMA (decision path) ----------------
// C = (Ah+Al)@(Wh+Wl)^T ~= Ah@Wh + Ah@Wl + Al@Wh  (error ~2^-17 rel).
// geluF=1: v = gelu(acc + bias2[b][n]); emit hi/lo bf16 (Chi/Clo), N-strided.
// geluF=0: f32 out to Cf (stride N), bias[n] only for n<Nb; gelu2 applies gelu to f32 out.
__global__ __launch_bounds__(256) void k_gemm128s(const u16* __restrict__ Ah, const u16* __restrict__ Al,
                                                  const u16* __restrict__ Wh, const u16* __restrict__ Wl,
                                                  const float* __restrict__ bias, const float* __restrict__ bias2,
                                                  u16* __restrict__ Chi, u16* __restrict__ Clo,
                                                  float* __restrict__ Cf,
                                                  int M, int N, int K, int Nb, int geluF, int gelu2) {
  __shared__ __align__(16) u16 sb[4*8192];   // 64 KB: sAh, sAl, sWh, sWl
  u16* sAh = sb;
  u16* sAl = sb + 8192;
  u16* sWh = sb + 16384;
  u16* sWl = sb + 24576;
  int tid = threadIdx.x;
  int wave = tid >> 6, lane = tid & 63;
  int quad = lane >> 4, col = lane & 15;
  int m0 = blockIdx.y * 128, n0 = blockIdx.x * 128;

  const u16 *pah[4], *pal[4], *pbh[4], *pbl[4];
#pragma unroll
  for (int p = 0; p < 4; ++p) {
    int c = p*256 + tid;
    int row = c >> 3;
    int sg = (c & 7) ^ (row & 7);
    size_t ao = (size_t)min(m0 + row, M - 1) * K + sg*8;
    size_t bo = (size_t)(n0 + row) * K + sg*8;
    pah[p] = Ah + ao; pal[p] = Al + ao;
    pbh[p] = Wh + bo; pbl[p] = Wl + bo;
  }

  int wm = (wave >> 1) * 64, wn = (wave & 1) * 64;
  f32x4 acc[4][4];
  f32x4 z4 = {0.f, 0.f, 0.f, 0.f};
#pragma unroll
  for (int i = 0; i < 4; ++i)
#pragma unroll
    for (int j = 0; j < 4; ++j) acc[i][j] = z4;

  for (int k0 = 0; k0 < K; k0 += 64) {
#pragma unroll
    for (int p = 0; p < 4; ++p) {
      int dst = (p*256 + wave*64) * 8;
      gload_lds16(pah[p], &sAh[dst]);
      gload_lds16(pal[p], &sAl[dst]);
      gload_lds16(pbh[p], &sWh[dst]);
      gload_lds16(pbl[p], &sWl[dst]);
      pah[p] += 64; pal[p] += 64; pbh[p] += 64; pbl[p] += 64;
    }
    __syncthreads();

#pragma unroll
    for (int kk = 0; kk < 2; ++kk) {
      int sr = quad + kk*4;
      short8 ah[4], al[4], bh[4], bl[4];
#pragma unroll
      for (int i = 0; i < 4; ++i) {
        int row = wm + i*16 + col;
        int off = row*64 + ((sr ^ (row & 7)) * 8);
        ah[i] = *(const short8*)&sAh[off];
        al[i] = *(const short8*)&sAl[off];
      }
#pragma unroll
      for (int j = 0; j < 4; ++j) {
        int row = wn + j*16 + col;
        int off = row*64 + ((sr ^ (row & 7)) * 8);
        bh[j] = *(const short8*)&sWh[off];
        bl[j] = *(const short8*)&sWl[off];
      }
#pragma unroll
      for (int i = 0; i < 4; ++i)
#pragma unroll
        for (int j = 0; j < 4; ++j) {
          acc[i][j] = __builtin_amdgcn_mfma_f32_16x16x32_bf16(ah[i], bh[j], acc[i][j], 0, 0, 0);
          acc[i][j] = __builtin_amdgcn_mfma_f32_16x16x32_bf16(ah[i], bl[j], acc[i][j], 0, 0, 0);
          acc[i][j] = __builtin_amdgcn_mfma_f32_16x16x32_bf16(al[i], bh[j], acc[i][j], 0, 0, 0);
        }
    }
    __syncthreads();
  }

  if (geluF) {
    // gelu + hi/lo bf16 emit, LDS-staged for coalesced stores
#pragma unroll
    for (int j = 0; j < 4; ++j) {
      int cc = wn + j*16 + col;
      float bv = bias ? bias[n0 + cc] : 0.f;
#pragma unroll
      for (int i = 0; i < 4; ++i)
#pragma unroll
        for (int ii = 0; ii < 4; ++ii) {
          int row = wm + i*16 + quad*4 + ii;
          int mg = m0 + row;
          float v = acc[i][j][ii] + bv;
          if (bias2) v += bias2[(size_t)(mg >> 8) * N + n0 + cc];
          v = gelu_exact(v);
          u16 hi = f2b(v);
          sb[row*128 + cc] = hi;
          sb[16384 + row*128 + cc] = f2b(v - b2f(hi));
        }
    }
    __syncthreads();
#pragma unroll
    for (int q = 0; q < 8; ++q) {
      int idx = q*256 + tid;
      int row = idx >> 4, c16 = idx & 15;
      int mg = m0 + row;
      if (mg < M) {
        *(float4*)(Chi + (size_t)mg * N + n0 + c16*8) = *(const float4*)&sb[row*128 + c16*8];
        *(float4*)(Clo + (size_t)mg * N + n0 + c16*8) = *(const float4*)&sb[16384 + row*128 + c16*8];
      }
    }
  } else {
#pragma unroll
    for (int j = 0; j < 4; ++j) {
      int ccg = n0 + wn + j*16 + col;
      float bv = (bias && ccg < Nb) ? bias[ccg] : 0.f;
#pragma unroll
      for (int i = 0; i < 4; ++i) {
        int r = m0 + wm + i*16 + quad*4;
#pragma unroll
        for (int ii = 0; ii < 4; ++ii) {
          if (r + ii < M) {
            float v = acc[i][j][ii] + bv;
            if (gelu2) v = gelu_exact(v);
            Cf[(size_t)(r + ii) * N + ccg] = v;
          }
        }
      }
    }
  }
}

// ---------------- decision: sign of (gelu'd h2) . (w3[1]-w3[0]) + (b3[1]-b3[0]) ----------------
// one wave per row; coalesced loads; shfl-reduce.
__global__ __launch_bounds__(256) void k_decision(const float* __restrict__ h2g, const float* __restrict__ w3,
                                                  const float* __restrict__ b3, float* __restrict__ sdec) {
  int wave = threadIdx.x >> 6, lane = threadIdx.x & 63;
  int r = blockIdx.x * 4 + wave;   // 16384 rows
  const float* hp = h2g + (size_t)r * 256;  // gelu'd, stride 256
  float d = hp[lane]       * (w3[192 + lane] - w3[lane])
          + hp[64 + lane]  * (w3[256 + lane] - w3[64 + lane])
          + hp[128 + lane] * (w3[320 + lane] - w3[128 + lane]);
#pragma unroll
  for (int m = 1; m <= 32; m <<= 1) d += __shfl_xor(d, m, 64);
  if (lane == 0) sdec[r] = (d + (b3[1] - b3[0]) > 0.f) ? 1.f : 0.f; // jnp.argmax ties -> 0
}

// ---------------- attention v6: v5 minus vsum/epsn, sd folded into sdm, setprio ----------------
__global__ __launch_bounds__(512, 4) void k_attn(const u16* __restrict__ Qh, const u16* __restrict__ Kh,
                                                 const u16* __restrict__ Vh, const float* __restrict__ sdec,
                                                 u16* __restrict__ O) {
  __shared__ __align__(16) u16 vsT[64*424];    // V^T swizzled: (d,n) at d*424 + cs*8 + (n&7)
  __shared__ __align__(16) u16 pst[8][16][72]; // per-wave P staging: [q][key64], stride 72
  __shared__ __align__(16) float sdm[416];     // mask table over keys (template rows); sdq via +64

  int b = blockIdx.x, h = blockIdx.y;
  int tid = threadIdx.x;
  int wave = tid >> 6, lane = tid & 63;
  int quad = lane >> 4, col = lane & 15;

  size_t base = ((size_t)(h*B_ + b))*NV*64;
  const u16* Qb = Qh + base;
  const u16* Kb = Kh + base;
  const u16* Vb = Vh + base;

  if (tid < 416)
    sdm[tid] = (tid < 129) ? 1.f : ((tid <= 384) ? sdec[b*SFL + tid - 129] : 0.f);

  for (int i = tid; i < 64*39; i += 512) {
    int d = i / 39, n = 385 + (i - d*39);
    vsT[d*424 + n] = 0;
  }
  for (int idx = tid; idx < NV*8; idx += 512) {
    int n = idx >> 3, seg = idx & 7;
    short8 v = *(const short8*)(Vb + (size_t)n*64 + seg*8);
    int c = n >> 3;
    int cs = (c < 48) ? ((c & ~7) | ((c + seg) & 7)) : c;
    int b2 = cs*8 + (n & 7);
#pragma unroll
    for (int j = 0; j < 8; ++j)
      vsT[(seg*8 + j)*424 + b2] = ((const u16*)&v)[j];
  }
  __syncthreads();

  const f32x4 z4 = {0.f, 0.f, 0.f, 0.f};

  for (int t = wave; t < 21; t += 8) {
    int qn_lane = t*16 + col;
    int pos = (qn_lane == 0) ? 0 : (min(qn_lane, 320) + 64);
    const u16* qp = Qb + (size_t)pos*64 + quad*8;
    short8 aq0 = *(const short8*)(qp);
    short8 aq1 = *(const short8*)(qp + 32);

    bool isTpl = (qn_lane >= 1 && qn_lane <= 64);
    bool isSearch = (qn_lane >= 65);
    float sdq = isSearch ? sdm[min(qn_lane + 64, 384)] : 1.f;

    float m_ = -1e30f, l_ = 0.f;
    f32x4 oc[4];
#pragma unroll
    for (int nt = 0; nt < 4; ++nt) oc[nt] = z4;

    for (int ch = 0; ch < 6; ++ch) {
      int key0c = ch*64;
      f32x4 acc4[4];
#pragma unroll
      for (int j = 0; j < 4; ++j) acc4[j] = z4;
      __builtin_amdgcn_s_setprio(1);
#pragma unroll
      for (int j = 0; j < 4; ++j) {
        const u16* kp = Kb + (size_t)(key0c + j*16 + col)*64;
        short8 k0 = *(const short8*)(kp + quad*8);
        short8 k1 = *(const short8*)(kp + 32 + quad*8);
        acc4[j] = __builtin_amdgcn_mfma_f32_16x16x32_bf16(k0, aq0, acc4[j], 0, 0, 0);
        acc4[j] = __builtin_amdgcn_mfma_f32_16x16x32_bf16(k1, aq1, acc4[j], 0, 0, 0);
      }
      __builtin_amdgcn_s_setprio(0);
      float cm = acc4[0][0];
#pragma unroll
      for (int j = 0; j < 4; ++j)
#pragma unroll
        for (int r = 0; r < 4; ++r)
          if (j || r) cm = fmaxf(cm, acc4[j][r]);
      cm = fmaxf(cm, __shfl_xor(cm, 16, 64));
      cm = fmaxf(cm, __shfl_xor(cm, 32, 64));
      float mn = fmaxf(m_, cm * SCALE_);
      float rnew = __expf(m_ - mn);
      m_ = mn;
      float rb[4];
#pragma unroll
      for (int r = 0; r < 4; ++r) rb[r] = __shfl(rnew, quad*4 + r, 64);
#pragma unroll
      for (int nt = 0; nt < 4; ++nt) {
        oc[nt][0] *= rb[0]; oc[nt][1] *= rb[1]; oc[nt][2] *= rb[2]; oc[nt][3] *= rb[3];
      }

      float ssum = 0.f;
#pragma unroll
      for (int j = 0; j < 4; ++j) {
        int key0 = key0c + j*16;
        float4 tm = make_float4(1.f, 1.f, 1.f, 1.f);
        if (isTpl) tm = *(const float4*)&sdm[key0 + quad*4];
        float a[4];
        const float* tmp = (const float*)&tm;
#pragma unroll
        for (int r = 0; r < 4; ++r) {
          int key = key0 + quad*4 + r;
          float msk = isTpl ? tmp[r]
                            : ((isSearch && key >= 1 && key <= 128) ? sdq : 1.f);
          a[r] = __expf(fmaf(acc4[j][r], SCALE_, -mn)) * msk;
          ssum += a[r];
        }
        uint2 pk;
        pk.x = (u32)f2b(a[0]) | ((u32)f2b(a[1]) << 16);
        pk.y = (u32)f2b(a[2]) | ((u32)f2b(a[3]) << 16);
        *(uint2*)&pst[wave][col][j*16 + quad*4] = pk;
      }
      ssum += __shfl_xor(ssum, 16, 64);
      ssum += __shfl_xor(ssum, 32, 64);
      l_ = l_ * rnew + ssum;

      asm volatile("" ::: "memory");
      __builtin_amdgcn_s_setprio(1);
#pragma unroll
      for (int st = 0; st < 2; ++st) {
        short8 pa = *(const short8*)&pst[wave][col][st*32 + quad*8];
        int step = ch*2 + st;
#pragma unroll
        for (int nt = 0; nt < 4; ++nt) {
          int d = nt*16 + col;
          int c = step*4 + quad;
          int cs = (c & ~7) | ((c + (d >> 3)) & 7);
          short8 bv = *(const short8*)&vsT[d*424 + cs*8];
          oc[nt] = __builtin_amdgcn_mfma_f32_16x16x32_bf16(pa, bv, oc[nt], 0, 0, 0);
        }
      }
      __builtin_amdgcn_s_setprio(0);
    }

    {
      const u16* kp = Kb + (size_t)384*64;
      short8 k0 = *(const short8*)(kp + quad*8);
      short8 k1 = *(const short8*)(kp + 32 + quad*8);
      f32x4 accE = z4;
      accE = __builtin_amdgcn_mfma_f32_16x16x32_bf16(k0, aq0, accE, 0, 0, 0);
      accE = __builtin_amdgcn_mfma_f32_16x16x32_bf16(k1, aq1, accE, 0, 0, 0);
      float cm = (quad == 0) ? accE[0] : -1e30f;
      cm = fmaxf(cm, __shfl_xor(cm, 16, 64));
      cm = fmaxf(cm, __shfl_xor(cm, 32, 64));
      float mn = fmaxf(m_, cm * SCALE_);
      float rnew = __expf(m_ - mn);
      m_ = mn;
      float rb[4];
#pragma unroll
      for (int r = 0; r < 4; ++r) rb[r] = __shfl(rnew, quad*4 + r, 64);
#pragma unroll
      for (int nt = 0; nt < 4; ++nt) {
        oc[nt][0] *= rb[0]; oc[nt][1] *= rb[1]; oc[nt][2] *= rb[2]; oc[nt][3] *= rb[3];
      }
      float mskE = isTpl ? sdm[384] : 1.f;
      float aE = (quad == 0) ? __expf(fmaf(accE[0], SCALE_, -mn)) * mskE : 0.f;
      float ssum = aE;
      ssum += __shfl_xor(ssum, 16, 64);
      ssum += __shfl_xor(ssum, 32, 64);
      l_ = l_ * rnew + ssum;

      uint2 pk;
      pk.x = (quad == 0) ? (u32)f2b(aE) : 0u;
      pk.y = 0u;
      *(uint2*)&pst[wave][col][quad*4] = pk;
      *(uint2*)&pst[wave][col][16 + quad*4] = make_uint2(0u, 0u);
      asm volatile("" ::: "memory");
      short8 pa = *(const short8*)&pst[wave][col][quad*8];
#pragma unroll
      for (int nt = 0; nt < 4; ++nt) {
        int d = nt*16 + col;
        short8 bv = *(const short8*)&vsT[d*424 + (48 + quad)*8];
        oc[nt] = __builtin_amdgcn_mfma_f32_16x16x32_bf16(pa, bv, oc[nt], 0, 0, 0);
      }
    }

    float lb[4];
#pragma unroll
    for (int r = 0; r < 4; ++r) lb[r] = __shfl(l_, quad*4 + r, 64);
#pragma unroll
    for (int r = 0; r < 4; ++r) {
      float invv = 1.f / (lb[r] + EPS_);
      int qn = t*16 + quad*4 + r;
      if (qn <= 320) {
#pragma unroll
        for (int nt = 0; nt < 4; ++nt)
          O[((size_t)(b*NQ + qn))*CDIM + h*HD + nt*16 + col] = f2b(oc[nt][r] * invv);
      }
    }
  }
}

extern "C" void kernel_launch(void* const* d_in, const int* in_sizes, int n_in,
                              void* d_out, int out_size, void* d_ws, size_t ws_size,
                              hipStream_t stream) {
  const float* x      = (const float*)d_in[0];
  const float* qkv_w  = (const float*)d_in[2];
  const float* qkv_b  = (const float*)d_in[3];
  const float* proj_w = (const float*)d_in[4];
  const float* proj_b = (const float*)d_in[5];
  const float* dp1_w  = (const float*)d_in[6];
  const float* dp1_b  = (const float*)d_in[7];
  const float* dp2_w  = (const float*)d_in[8];
  const float* dp2_b  = (const float*)d_in[9];
  const float* dp3_w  = (const float*)d_in[10];
  const float* dp3_b  = (const float*)d_in[11];
  float* out = (float*)d_out;

  char* ws = (char*)d_ws;
  size_t off = 0;
  auto alloc = [&](size_t bytes) -> void* {
    void* p = ws + off;
    off += (bytes + 255) & ~(size_t)255;
    return p;
  };
  u16*  xb      = (u16*)alloc((size_t)MQ * CDIM * 2);       // 37.8 MB
  u16*  qkv_wb  = (u16*)alloc((size_t)2304 * CDIM * 2);     // 3.5 MB
  u16*  proj_wb = (u16*)alloc((size_t)CDIM * CDIM * 2);     // 1.2 MB
  u16*  qh      = (u16*)alloc((size_t)NH * B_ * NV * 64 * 2); // 37.8 MB
  u16*  kh      = (u16*)alloc((size_t)NH * B_ * NV * 64 * 2); // 37.8 MB
  u16*  vh      = (u16*)alloc((size_t)NH * B_ * NV * 64 * 2); // 37.8 MB
  u16*  Obuf    = (u16*)alloc((size_t)MP * CDIM * 2);       // 31.6 MB
  float* tgt    = (float*)alloc((size_t)B_ * CDIM * 4);
  float* tb     = (float*)alloc((size_t)B_ * 384 * 4);      // dp1 tgt-term (incl dp1_b)
  u16*  xsh     = (u16*)alloc((size_t)MD * CDIM * 2);       // 25.2 MB (x search rows, hi)
  u16*  xsl     = (u16*)alloc((size_t)MD * CDIM * 2);       // 25.2 MB (lo)
  u16*  w1h     = (u16*)alloc((size_t)384 * CDIM * 2);
  u16*  w1l     = (u16*)alloc((size_t)384 * CDIM * 2);
  u16*  w2h     = (u16*)alloc((size_t)256 * 384 * 2);
  u16*  w2l     = (u16*)alloc((size_t)256 * 384 * 2);
  u16*  h1h     = (u16*)alloc((size_t)MD * 384 * 2);        // 12.6 MB
  u16*  h1l     = (u16*)alloc((size_t)MD * 384 * 2);        // 12.6 MB
  float* h2f    = (float*)alloc((size_t)MD * 256 * 4);      // 16.8 MB (gelu'd, padded)
  float* sdec   = (float*)alloc((size_t)MD * 4);

  // fused prep: x convert + search-row split; all weight converts/splits; tgt mean
  k_prep_x<<<dim3(MQ), dim3(192), 0, stream>>>(x, (ushort4*)xb, (ushort4*)xsh, (ushort4*)xsl);
  k_prep_w<<<dim3(PR3/256), dim3(256), 0, stream>>>(qkv_w, proj_w, dp1_w, dp2_w,
                                                    (ushort4*)qkv_wb, (ushort4*)proj_wb,
                                                    (ushort4*)w1h, (ushort4*)w1l,
                                                    (ushort4*)w2h, (ushort4*)w2l);
  k_tgt<<<dim3(B_), dim3(CDIM), 0, stream>>>(x, tgt);

  // qkv = x @ qkv_w.T + qkv_b  (bf16 out, scattered to head-major Q/K/V)
  k_gemm128<<<dim3(2304/128, (MQ + 127)/128), dim3(256), 0, stream>>>(xb, qkv_wb, qkv_b, qh, kh, vh,
                                                                      (float*)nullptr, MQ, 2304, CDIM, 0);
  // tb = tgt @ dp1_w[:,768:].T + dp1_b
  k_tb<<<dim3(B_), dim3(256), 0, stream>>>(tgt, dp1_w, dp1_b, tb);
  // dp1: h1 = gelu(Xs @ W1a.T + tb), split-fp32 via 3x bf16 MFMA, emits h1 hi/lo
  k_gemm128s<<<dim3(384/128, MD/128), dim3(256), 0, stream>>>(xsh, xsl, w1h, w1l,
                                                              nullptr, tb, h1h, h1l, nullptr,
                                                              MD, 384, CDIM, 384, 1, 0);
  // dp2: h2f = gelu(h1 @ W2.T + b2) (f32, N padded to 256)
  k_gemm128s<<<dim3(256/128, MD/128), dim3(256), 0, stream>>>(h1h, h1l, w2h, w2l,
                                                              dp2_b, nullptr, nullptr, nullptr, h2f,
                                                              MD, 256, 384, 192, 0, 1);
  k_decision<<<dim3(MD/4), dim3(256), 0, stream>>>(h2f, dp3_w, dp3_b, sdec);

  // attention (512 threads / 8 waves per block)
  k_attn<<<dim3(B_, NH), dim3(512), 0, stream>>>(qh, kh, vh, sdec, Obuf);

  // out = O @ proj_w.T + proj_b (fp32 out)
  k_gemm128<<<dim3(CDIM/128, (MP + 127)/128), dim3(256), 0, stream>>>(Obuf, proj_wb, proj_b,
                                                                      nullptr, nullptr, nullptr, out,
                                                                      MP, CDIM, CDIM, 1);
}

// Round 8
// 598.963 us; speedup vs baseline: 1.4340x; 1.0009x over previous
//
#include <hip/hip_runtime.h>
#include <cmath>

typedef unsigned short u16;
typedef unsigned int u32;
typedef __attribute__((ext_vector_type(8))) short short8;
typedef __attribute__((ext_vector_type(4))) float f32x4;

#define B_    64
#define NV    385
#define CDIM  768
#define NQ    321
#define SFL   256
#define NH    12
#define HD    64
#define MQ    (B_*NV)   /* 24640 */
#define MP    (B_*NQ)   /* 20544 */
#define MD    (B_*SFL)  /* 16384 */
#define SCALE_ 0.125f
#define EPS_   1e-6f

__device__ __forceinline__ u16 f2b(float f) {
  u32 x = __float_as_uint(f);
  return (u16)((x + 0x7FFFu + ((x >> 16) & 1u)) >> 16);
}
__device__ __forceinline__ float b2f(u16 h) {
  return __uint_as_float((u32)h << 16);
}

__device__ __forceinline__ void gload_lds16(const void* g, void* l) {
  __builtin_amdgcn_global_load_lds(
      (const __attribute__((address_space(1))) u32*)g,
      (__attribute__((address_space(3))) u32*)l,
      16, 0, 0);
}

// bijective XCD swizzle (m204): contiguous logical blocks -> one XCD
__device__ __forceinline__ int xcd_swz(int lin, int nwg) {
  int xcd = lin & 7, idx = lin >> 3;
  int q = nwg >> 3, r = nwg & 7;
  int base = (xcd < r) ? xcd * (q + 1) : r * (q + 1) + (xcd - r) * q;
  return base + idx;
}

__device__ __forceinline__ float gelu_exact(float x) {
  return 0.5f * x * (1.f + erff(x * 0.70710678118654752f));
}

// ---------------- fused x prep: bf16 convert + search-row hi/lo split ----------------
__global__ void k_prep_x(const float* __restrict__ x, ushort4* __restrict__ xb,
                         ushort4* __restrict__ xsh, ushort4* __restrict__ xsl) {
  int row = blockIdx.x;            // 24640 rows
  int tid = threadIdx.x;           // 192 threads (float4 per thread)
  float4 v = ((const float4*)x)[(size_t)row*192 + tid];
  ushort4 h;
  h.x = f2b(v.x); h.y = f2b(v.y); h.z = f2b(v.z); h.w = f2b(v.w);
  xb[(size_t)row*192 + tid] = h;
  int b = row / NV, n = row - b*NV;
  if (n >= 129) {
    ushort4 l;
    l.x = f2b(v.x - b2f(h.x)); l.y = f2b(v.y - b2f(h.y));
    l.z = f2b(v.z - b2f(h.z)); l.w = f2b(v.w - b2f(h.w));
    size_t s = (size_t)(b*256 + n - 129)*192 + tid;
    xsh[s] = h; xsl[s] = l;
  }
}

// ---------------- fused weight prep: qkv/proj converts + dp1/dp2 hi-lo splits ----------------
#define PR0 442368              /* 2304*192: qkv_w */
#define PR1 (PR0 + 147456)      /* 768*192: proj_w */
#define PR2 (PR1 + 73728)       /* 384*192: dp1_w cols 0..767 */
#define PR3 (PR2 + 24576)       /* 256*96: dp2_w padded */
__global__ void k_prep_w(const float* __restrict__ qkv_w, const float* __restrict__ proj_w,
                         const float* __restrict__ dp1_w, const float* __restrict__ dp2_w,
                         ushort4* __restrict__ qkv_wb, ushort4* __restrict__ proj_wb,
                         ushort4* __restrict__ w1h, ushort4* __restrict__ w1l,
                         ushort4* __restrict__ w2h, ushort4* __restrict__ w2l) {
  int i = blockIdx.x * 256 + threadIdx.x;
  if (i < PR0) {
    float4 v = ((const float4*)qkv_w)[i];
    ushort4 h; h.x = f2b(v.x); h.y = f2b(v.y); h.z = f2b(v.z); h.w = f2b(v.w);
    qkv_wb[i] = h;
  } else if (i < PR1) {
    int j = i - PR0;
    float4 v = ((const float4*)proj_w)[j];
    ushort4 h; h.x = f2b(v.x); h.y = f2b(v.y); h.z = f2b(v.z); h.w = f2b(v.w);
    proj_wb[j] = h;
  } else if (i < PR2) {
    int j = i - PR1;
    int r = j / 192, c4 = j - r*192;
    float4 v = *(const float4*)(dp1_w + (size_t)r*1536 + c4*4);
    ushort4 h, l;
    h.x = f2b(v.x); l.x = f2b(v.x - b2f(h.x));
    h.y = f2b(v.y); l.y = f2b(v.y - b2f(h.y));
    h.z = f2b(v.z); l.z = f2b(v.z - b2f(h.z));
    h.w = f2b(v.w); l.w = f2b(v.w - b2f(h.w));
    w1h[j] = h; w1l[j] = l;
  } else if (i < PR3) {
    int j = i - PR2;
    int r = j / 96, c4 = j - r*96;
    ushort4 h = {0,0,0,0}, l = {0,0,0,0};
    if (r < 192) {
      float4 v = *(const float4*)(dp2_w + (size_t)r*384 + c4*4);
      h.x = f2b(v.x); l.x = f2b(v.x - b2f(h.x));
      h.y = f2b(v.y); l.y = f2b(v.y - b2f(h.y));
      h.z = f2b(v.z); l.z = f2b(v.z - b2f(h.z));
      h.w = f2b(v.w); l.w = f2b(v.w - b2f(h.w));
    }
    w2h[j] = h; w2l[j] = l;
  }
}

// ---------------- tgt_rep = mean over x[:, 65:129, :] ----------------
__global__ void k_tgt(const float* __restrict__ x, float* __restrict__ tgt) {
  int b = blockIdx.x, c = threadIdx.x; // block = 768 threads
  float s = 0.f;
  for (int j = 0; j < 64; ++j) s += x[((size_t)(b*NV + 65 + j))*CDIM + c];
  tgt[b*CDIM + c] = s * (1.f/64.f);
}

// ---------------- tb = tgt @ dp1_w[:,768:].T + dp1_b  (64x384x768, block per batch) ----------------
__global__ __launch_bounds__(256) void k_tb(const float* __restrict__ tgt, const float* __restrict__ dp1_w,
                                            const float* __restrict__ dp1_b, float* __restrict__ tb) {
  __shared__ float tg[768];
  int b = blockIdx.x, tid = threadIdx.x;
  for (int i = tid; i < 768; i += 256) tg[i] = tgt[b*768 + i];
  __syncthreads();
  for (int n = tid; n < 384; n += 256) {
    const float* w = dp1_w + (size_t)n*1536 + 768;
    float s = dp1_b[n];
    for (int k = 0; k < 768; k += 4) {
      float4 wv = *(const float4*)(w + k);
      s += tg[k]*wv.x + tg[k+1]*wv.y + tg[k+2]*wv.z + tg[k+3]*wv.w;
    }
    tb[b*384 + n] = s;
  }
}

// ---------------- 128x128 bf16 MFMA GEMM, BK=64, XOR-swizzled LDS, XCD-swizzled grid ----------------
// mode 0 -> qkv path: scatter bf16 C into head-major Qh/Kh/Vh [h][b][n][64]
// mode 1 -> f32 out (direct, used for proj)
// XCD swizzle is COLUMN-major: each XCD owns consecutive column strips -> its 196KB
// weight panel stays L2-resident; the large A matrix lives in L3 after first touch.
__global__ __launch_bounds__(256) void k_gemm128(const u16* __restrict__ A, const u16* __restrict__ W,
                                                 const float* __restrict__ bias,
                                                 u16* __restrict__ Qh, u16* __restrict__ Kh, u16* __restrict__ Vh,
                                                 float* __restrict__ Cf,
                                                 int M, int N, int K, int mode) {
  __shared__ __align__(16) u16 sbuf[128*128];  // 32 KB: As=sbuf[0:8192), Ws=sbuf[8192:16384)
  u16* As = sbuf;
  u16* Ws = sbuf + 8192;
  int tid = threadIdx.x;
  int wave = tid >> 6, lane = tid & 63;
  int quad = lane >> 4, col = lane & 15;
  // column-major linearization + bijective XCD remap (T1)
  int gy = gridDim.y;
  int lin = blockIdx.x * gy + blockIdx.y;
  int s = xcd_swz(lin, gridDim.x * gy);
  int bx = s / gy, by = s % gy;
  int m0 = by * 128, n0 = bx * 128;

  const u16* pa[4];
  const u16* pb[4];
#pragma unroll
  for (int p = 0; p < 4; ++p) {
    int c = p*256 + tid;
    int row = c >> 3;
    int sg = (c & 7) ^ (row & 7);          // XOR swizzle (source-side)
    pa[p] = A + (size_t)min(m0 + row, M - 1) * K + sg*8;
    pb[p] = W + (size_t)(n0 + row) * K + sg*8;
  }

  int wm = (wave >> 1) * 64, wn = (wave & 1) * 64;
  f32x4 acc[4][4];
  f32x4 z4 = {0.f, 0.f, 0.f, 0.f};
#pragma unroll
  for (int i = 0; i < 4; ++i)
#pragma unroll
    for (int j = 0; j < 4; ++j) acc[i][j] = z4;

  for (int k0 = 0; k0 < K; k0 += 64) {
#pragma unroll
    for (int p = 0; p < 4; ++p) {
      gload_lds16(pa[p], &As[(p*256 + wave*64) * 8]);
      gload_lds16(pb[p], &Ws[(p*256 + wave*64) * 8]);
      pa[p] += 64; pb[p] += 64;
    }
    __syncthreads();

#pragma unroll
    for (int kk = 0; kk < 2; ++kk) {
      int sr = quad + kk*4;                // 16B chunk index within the 64-u16 row
      short8 af[4], bf[4];
#pragma unroll
      for (int i = 0; i < 4; ++i) {
        int row = wm + i*16 + col;
        af[i] = *(const short8*)&As[row*64 + ((sr ^ (row & 7)) * 8)];
      }
#pragma unroll
      for (int j = 0; j < 4; ++j) {
        int row = wn + j*16 + col;
        bf[j] = *(const short8*)&Ws[row*64 + ((sr ^ (row & 7)) * 8)];
      }
#pragma unroll
      for (int i = 0; i < 4; ++i)
#pragma unroll
        for (int j = 0; j < 4; ++j)
          acc[i][j] = __builtin_amdgcn_mfma_f32_16x16x32_bf16(af[i], bf[j], acc[i][j], 0, 0, 0);
    }
    __syncthreads();
  }

  if (mode == 0) {
    // stage C-tile (bf16) in sbuf[128][128], then scatter to head-major Q/K/V
#pragma unroll
    for (int j = 0; j < 4; ++j) {
      int cc = wn + j*16 + col;
      float bv = bias ? bias[n0 + cc] : 0.f;
#pragma unroll
      for (int i = 0; i < 4; ++i)
#pragma unroll
        for (int ii = 0; ii < 4; ++ii) {
          int row = wm + i*16 + quad*4 + ii;
          sbuf[row*128 + cc] = f2b(acc[i][j][ii] + bv);
        }
    }
    __syncthreads();
#pragma unroll
    for (int q = 0; q < 8; ++q) {
      int idx = q*256 + tid;
      int row = idx >> 4, c16 = idx & 15;
      int mg = m0 + row;
      if (mg < M) {
        int n = n0 + c16*8;
        int which = n / 768;               // 128-col tiles never straddle a 768 boundary
        int rem = n - which*768;
        int hh = rem >> 6, d0 = rem & 63;
        int bb = mg / NV, nn = mg - bb*NV;
        u16* dst = (which == 0) ? Qh : (which == 1) ? Kh : Vh;
        *(float4*)(dst + (((size_t)hh*B_ + bb)*NV + nn)*64 + d0) = *(const float4*)&sbuf[row*128 + c16*8];
      }
    }
  } else {
#pragma unroll
    for (int j = 0; j < 4; ++j) {
      int cc = n0 + wn + j*16 + col;
      float bv = bias ? bias[cc] : 0.f;
#pragma unroll
      for (int i = 0; i < 4; ++i) {
        int r = m0 + wm + i*16 + quad*4;
#pragma unroll
        for (int ii = 0; ii < 4; ++ii) {
          if (r + ii < M) Cf[(size_t)(r + ii) * N + cc] = acc[i][j][ii] + bv;
        }
      }
    }
  }
}

// ---------------- split-fp32 GEMM via 3x bf16 MFMA (decision path) ----------------
__global__ __launch_bounds__(256) void k_gemm128s(const u16* __restrict__ Ah, const u16* __restrict__ Al,
                                                  const u16* __restrict__ Wh, const u16* __restrict__ Wl,
                                                  const float* __restrict__ bias, const float* __restrict__ bias2,
                                                  u16* __restrict__ Chi, u16* __restrict__ Clo,
                                                  float* __restrict__ Cf,
                                                  int M, int N, int K, int Nb, int geluF, int gelu2) {
  __shared__ __align__(16) u16 sb[4*8192];   // 64 KB: sAh, sAl, sWh, sWl
  u16* sAh = sb;
  u16* sAl = sb + 8192;
  u16* sWh = sb + 16384;
  u16* sWl = sb + 24576;
  int tid = threadIdx.x;
  int wave = tid >> 6, lane = tid & 63;
  int quad = lane >> 4, col = lane & 15;
  int m0 = blockIdx.y * 128, n0 = blockIdx.x * 128;

  const u16 *pah[4], *pal[4], *pbh[4], *pbl[4];
#pragma unroll
  for (int p = 0; p < 4; ++p) {
    int c = p*256 + tid;
    int row = c >> 3;
    int sg = (c & 7) ^ (row & 7);
    size_t ao = (size_t)min(m0 + row, M - 1) * K + sg*8;
    size_t bo = (size_t)(n0 + row) * K + sg*8;
    pah[p] = Ah + ao; pal[p] = Al + ao;
    pbh[p] = Wh + bo; pbl[p] = Wl + bo;
  }

  int wm = (wave >> 1) * 64, wn = (wave & 1) * 64;
  f32x4 acc[4][4];
  f32x4 z4 = {0.f, 0.f, 0.f, 0.f};
#pragma unroll
  for (int i = 0; i < 4; ++i)
#pragma unroll
    for (int j = 0; j < 4; ++j) acc[i][j] = z4;

  for (int k0 = 0; k0 < K; k0 += 64) {
#pragma unroll
    for (int p = 0; p < 4; ++p) {
      int dst = (p*256 + wave*64) * 8;
      gload_lds16(pah[p], &sAh[dst]);
      gload_lds16(pal[p], &sAl[dst]);
      gload_lds16(pbh[p], &sWh[dst]);
      gload_lds16(pbl[p], &sWl[dst]);
      pah[p] += 64; pal[p] += 64; pbh[p] += 64; pbl[p] += 64;
    }
    __syncthreads();

#pragma unroll
    for (int kk = 0; kk < 2; ++kk) {
      int sr = quad + kk*4;
      short8 ah[4], al[4], bh[4], bl[4];
#pragma unroll
      for (int i = 0; i < 4; ++i) {
        int row = wm + i*16 + col;
        int off = row*64 + ((sr ^ (row & 7)) * 8);
        ah[i] = *(const short8*)&sAh[off];
        al[i] = *(const short8*)&sAl[off];
      }
#pragma unroll
      for (int j = 0; j < 4; ++j) {
        int row = wn + j*16 + col;
        int off = row*64 + ((sr ^ (row & 7)) * 8);
        bh[j] = *(const short8*)&sWh[off];
        bl[j] = *(const short8*)&sWl[off];
      }
#pragma unroll
      for (int i = 0; i < 4; ++i)
#pragma unroll
        for (int j = 0; j < 4; ++j) {
          acc[i][j] = __builtin_amdgcn_mfma_f32_16x16x32_bf16(ah[i], bh[j], acc[i][j], 0, 0, 0);
          acc[i][j] = __builtin_amdgcn_mfma_f32_16x16x32_bf16(ah[i], bl[j], acc[i][j], 0, 0, 0);
          acc[i][j] = __builtin_amdgcn_mfma_f32_16x16x32_bf16(al[i], bh[j], acc[i][j], 0, 0, 0);
        }
    }
    __syncthreads();
  }

  if (geluF) {
    // gelu + hi/lo bf16 emit, LDS-staged for coalesced stores
#pragma unroll
    for (int j = 0; j < 4; ++j) {
      int cc = wn + j*16 + col;
      float bv = bias ? bias[n0 + cc] : 0.f;
#pragma unroll
      for (int i = 0; i < 4; ++i)
#pragma unroll
        for (int ii = 0; ii < 4; ++ii) {
          int row = wm + i*16 + quad*4 + ii;
          int mg = m0 + row;
          float v = acc[i][j][ii] + bv;
          if (bias2) v += bias2[(size_t)(mg >> 8) * N + n0 + cc];
          v = gelu_exact(v);
          u16 hi = f2b(v);
          sb[row*128 + cc] = hi;
          sb[16384 + row*128 + cc] = f2b(v - b2f(hi));
        }
    }
    __syncthreads();
#pragma unroll
    for (int q = 0; q < 8; ++q) {
      int idx = q*256 + tid;
      int row = idx >> 4, c16 = idx & 15;
      int mg = m0 + row;
      if (mg < M) {
        *(float4*)(Chi + (size_t)mg * N + n0 + c16*8) = *(const float4*)&sb[row*128 + c16*8];
        *(float4*)(Clo + (size_t)mg * N + n0 + c16*8) = *(const float4*)&sb[16384 + row*128 + c16*8];
      }
    }
  } else {
#pragma unroll
    for (int j = 0; j < 4; ++j) {
      int ccg = n0 + wn + j*16 + col;
      float bv = (bias && ccg < Nb) ? bias[ccg] : 0.f;
#pragma unroll
      for (int i = 0; i < 4; ++i) {
        int r = m0 + wm + i*16 + quad*4;
#pragma unroll
        for (int ii = 0; ii < 4; ++ii) {
          if (r + ii < M) {
            float v = acc[i][j][ii] + bv;
            if (gelu2) v = gelu_exact(v);
            Cf[(size_t)(r + ii) * N + ccg] = v;
          }
        }
      }
    }
  }
}

// ---------------- decision: sign of (gelu'd h2) . (w3[1]-w3[0]) + (b3[1]-b3[0]) ----------------
__global__ __launch_bounds__(256) void k_decision(const float* __restrict__ h2g, const float* __restrict__ w3,
                                                  const float* __restrict__ b3, float* __restrict__ sdec) {
  int wave = threadIdx.x >> 6, lane = threadIdx.x & 63;
  int r = blockIdx.x * 4 + wave;   // 16384 rows
  const float* hp = h2g + (size_t)r * 256;  // gelu'd, stride 256
  float d = hp[lane]       * (w3[192 + lane] - w3[lane])
          + hp[64 + lane]  * (w3[256 + lane] - w3[64 + lane])
          + hp[128 + lane] * (w3[320 + lane] - w3[128 + lane]);
#pragma unroll
  for (int m = 1; m <= 32; m <<= 1) d += __shfl_xor(d, m, 64);
  if (lane == 0) sdec[r] = (d + (b3[1] - b3[0]) > 0.f) ? 1.f : 0.f; // jnp.argmax ties -> 0
}

// ---------------- attention v7: v6 + q-tile split across blockIdx.z ----------------
// 768 blocks -> 1536 (z=0: tiles 0..10, z=1: tiles 11..20): exactly 3 residency
// rounds (2 blocks/CU), per-wave critical path 3 -> 2 tiles. V^T staged per block.
__global__ __launch_bounds__(512, 4) void k_attn(const u16* __restrict__ Qh, const u16* __restrict__ Kh,
                                                 const u16* __restrict__ Vh, const float* __restrict__ sdec,
                                                 u16* __restrict__ O) {
  __shared__ __align__(16) u16 vsT[64*424];    // V^T swizzled: (d,n) at d*424 + cs*8 + (n&7)
  __shared__ __align__(16) u16 pst[8][16][72]; // per-wave P staging: [q][key64], stride 72
  __shared__ __align__(16) float sdm[416];     // mask table over keys (template rows); sdq via +64

  int b = blockIdx.x, h = blockIdx.y;
  int tz = blockIdx.z;
  int tid = threadIdx.x;
  int wave = tid >> 6, lane = tid & 63;
  int quad = lane >> 4, col = lane & 15;

  size_t base = ((size_t)(h*B_ + b))*NV*64;
  const u16* Qb = Qh + base;
  const u16* Kb = Kh + base;
  const u16* Vb = Vh + base;

  if (tid < 416)
    sdm[tid] = (tid < 129) ? 1.f : ((tid <= 384) ? sdec[b*SFL + tid - 129] : 0.f);

  for (int i = tid; i < 64*39; i += 512) {
    int d = i / 39, n = 385 + (i - d*39);
    vsT[d*424 + n] = 0;
  }
  for (int idx = tid; idx < NV*8; idx += 512) {
    int n = idx >> 3, seg = idx & 7;
    short8 v = *(const short8*)(Vb + (size_t)n*64 + seg*8);
    int c = n >> 3;
    int cs = (c < 48) ? ((c & ~7) | ((c + seg) & 7)) : c;
    int b2 = cs*8 + (n & 7);
#pragma unroll
    for (int j = 0; j < 8; ++j)
      vsT[(seg*8 + j)*424 + b2] = ((const u16*)&v)[j];
  }
  __syncthreads();

  const f32x4 z4 = {0.f, 0.f, 0.f, 0.f};
  int tEnd = min(11*(tz + 1), 21);

  for (int t = 11*tz + wave; t < tEnd; t += 8) {
    int qn_lane = t*16 + col;
    int pos = (qn_lane == 0) ? 0 : (min(qn_lane, 320) + 64);
    const u16* qp = Qb + (size_t)pos*64 + quad*8;
    short8 aq0 = *(const short8*)(qp);
    short8 aq1 = *(const short8*)(qp + 32);

    bool isTpl = (qn_lane >= 1 && qn_lane <= 64);
    bool isSearch = (qn_lane >= 65);
    float sdq = isSearch ? sdm[min(qn_lane + 64, 384)] : 1.f;

    float m_ = -1e30f, l_ = 0.f;
    f32x4 oc[4];
#pragma unroll
    for (int nt = 0; nt < 4; ++nt) oc[nt] = z4;

    for (int ch = 0; ch < 6; ++ch) {
      int key0c = ch*64;
      f32x4 acc4[4];
#pragma unroll
      for (int j = 0; j < 4; ++j) acc4[j] = z4;
      __builtin_amdgcn_s_setprio(1);
#pragma unroll
      for (int j = 0; j < 4; ++j) {
        const u16* kp = Kb + (size_t)(key0c + j*16 + col)*64;
        short8 k0 = *(const short8*)(kp + quad*8);
        short8 k1 = *(const short8*)(kp + 32 + quad*8);
        acc4[j] = __builtin_amdgcn_mfma_f32_16x16x32_bf16(k0, aq0, acc4[j], 0, 0, 0);
        acc4[j] = __builtin_amdgcn_mfma_f32_16x16x32_bf16(k1, aq1, acc4[j], 0, 0, 0);
      }
      __builtin_amdgcn_s_setprio(0);
      float cm = acc4[0][0];
#pragma unroll
      for (int j = 0; j < 4; ++j)
#pragma unroll
        for (int r = 0; r < 4; ++r)
          if (j || r) cm = fmaxf(cm, acc4[j][r]);
      cm = fmaxf(cm, __shfl_xor(cm, 16, 64));
      cm = fmaxf(cm, __shfl_xor(cm, 32, 64));
      float mn = fmaxf(m_, cm * SCALE_);
      float rnew = __expf(m_ - mn);
      m_ = mn;
      float rb[4];
#pragma unroll
      for (int r = 0; r < 4; ++r) rb[r] = __shfl(rnew, quad*4 + r, 64);
#pragma unroll
      for (int nt = 0; nt < 4; ++nt) {
        oc[nt][0] *= rb[0]; oc[nt][1] *= rb[1]; oc[nt][2] *= rb[2]; oc[nt][3] *= rb[3];
      }

      float ssum = 0.f;
#pragma unroll
      for (int j = 0; j < 4; ++j) {
        int key0 = key0c + j*16;
        float4 tm = make_float4(1.f, 1.f, 1.f, 1.f);
        if (isTpl) tm = *(const float4*)&sdm[key0 + quad*4];
        float a[4];
        const float* tmp = (const float*)&tm;
#pragma unroll
        for (int r = 0; r < 4; ++r) {
          int key = key0 + quad*4 + r;
          float msk = isTpl ? tmp[r]
                            : ((isSearch && key >= 1 && key <= 128) ? sdq : 1.f);
          a[r] = __expf(fmaf(acc4[j][r], SCALE_, -mn)) * msk;
          ssum += a[r];
        }
        uint2 pk;
        pk.x = (u32)f2b(a[0]) | ((u32)f2b(a[1]) << 16);
        pk.y = (u32)f2b(a[2]) | ((u32)f2b(a[3]) << 16);
        *(uint2*)&pst[wave][col][j*16 + quad*4] = pk;
      }
      ssum += __shfl_xor(ssum, 16, 64);
      ssum += __shfl_xor(ssum, 32, 64);
      l_ = l_ * rnew + ssum;

      asm volatile("" ::: "memory");
      __builtin_amdgcn_s_setprio(1);
#pragma unroll
      for (int st = 0; st < 2; ++st) {
        short8 pa = *(const short8*)&pst[wave][col][st*32 + quad*8];
        int step = ch*2 + st;
#pragma unroll
        for (int nt = 0; nt < 4; ++nt) {
          int d = nt*16 + col;
          int c = step*4 + quad;
          int cs = (c & ~7) | ((c + (d >> 3)) & 7);
          short8 bv = *(const short8*)&vsT[d*424 + cs*8];
          oc[nt] = __builtin_amdgcn_mfma_f32_16x16x32_bf16(pa, bv, oc[nt], 0, 0, 0);
        }
      }
      __builtin_amdgcn_s_setprio(0);
    }

    {
      const u16* kp = Kb + (size_t)384*64;
      short8 k0 = *(const short8*)(kp + quad*8);
      short8 k1 = *(const short8*)(kp + 32 + quad*8);
      f32x4 accE = z4;
      accE = __builtin_amdgcn_mfma_f32_16x16x32_bf16(k0, aq0, accE, 0, 0, 0);
      accE = __builtin_amdgcn_mfma_f32_16x16x32_bf16(k1, aq1, accE, 0, 0, 0);
      float cm = (quad == 0) ? accE[0] : -1e30f;
      cm = fmaxf(cm, __shfl_xor(cm, 16, 64));
      cm = fmaxf(cm, __shfl_xor(cm, 32, 64));
      float mn = fmaxf(m_, cm * SCALE_);
      float rnew = __expf(m_ - mn);
      m_ = mn;
      float rb[4];
#pragma unroll
      for (int r = 0; r < 4; ++r) rb[r] = __shfl(rnew, quad*4 + r, 64);
#pragma unroll
      for (int nt = 0; nt < 4; ++nt) {
        oc[nt][0] *= rb[0]; oc[nt][1] *= rb[1]; oc[nt][2] *= rb[2]; oc[nt][3] *= rb[3];
      }
      float mskE = isTpl ? sdm[384] : 1.f;
      float aE = (quad == 0) ? __expf(fmaf(accE[0], SCALE_, -mn)) * mskE : 0.f;
      float ssum = aE;
      ssum += __shfl_xor(ssum, 16, 64);
      ssum += __shfl_xor(ssum, 32, 64);
      l_ = l_ * rnew + ssum;

      uint2 pk;
      pk.x = (quad == 0) ? (u32)f2b(aE) : 0u;
      pk.y = 0u;
      *(uint2*)&pst[wave][col][quad*4] = pk;
      *(uint2*)&pst[wave][col][16 + quad*4] = make_uint2(0u, 0u);
      asm volatile("" ::: "memory");
      short8 pa = *(const short8*)&pst[wave][col][quad*8];
#pragma unroll
      for (int nt = 0; nt < 4; ++nt) {
        int d = nt*16 + col;
        short8 bv = *(const short8*)&vsT[d*424 + (48 + quad)*8];
        oc[nt] = __builtin_amdgcn_mfma_f32_16x16x32_bf16(pa, bv, oc[nt], 0, 0, 0);
      }
    }

    float lb[4];
#pragma unroll
    for (int r = 0; r < 4; ++r) lb[r] = __shfl(l_, quad*4 + r, 64);
#pragma unroll
    for (int r = 0; r < 4; ++r) {
      float invv = 1.f / (lb[r] + EPS_);
      int qn = t*16 + quad*4 + r;
      if (qn <= 320) {
#pragma unroll
        for (int nt = 0; nt < 4; ++nt)
          O[((size_t)(b*NQ + qn))*CDIM + h*HD + nt*16 + col] = f2b(oc[nt][r] * invv);
      }
    }
  }
}

extern "C" void kernel_launch(void* const* d_in, const int* in_sizes, int n_in,
                              void* d_out, int out_size, void* d_ws, size_t ws_size,
                              hipStream_t stream) {
  const float* x      = (const float*)d_in[0];
  const float* qkv_w  = (const float*)d_in[2];
  const float* qkv_b  = (const float*)d_in[3];
  const float* proj_w = (const float*)d_in[4];
  const float* proj_b = (const float*)d_in[5];
  const float* dp1_w  = (const float*)d_in[6];
  const float* dp1_b  = (const float*)d_in[7];
  const float* dp2_w  = (const float*)d_in[8];
  const float* dp2_b  = (const float*)d_in[9];
  const float* dp3_w  = (const float*)d_in[10];
  const float* dp3_b  = (const float*)d_in[11];
  float* out = (float*)d_out;

  char* ws = (char*)d_ws;
  size_t off = 0;
  auto alloc = [&](size_t bytes) -> void* {
    void* p = ws + off;
    off += (bytes + 255) & ~(size_t)255;
    return p;
  };
  u16*  xb      = (u16*)alloc((size_t)MQ * CDIM * 2);       // 37.8 MB
  u16*  qkv_wb  = (u16*)alloc((size_t)2304 * CDIM * 2);     // 3.5 MB
  u16*  proj_wb = (u16*)alloc((size_t)CDIM * CDIM * 2);     // 1.2 MB
  u16*  qh      = (u16*)alloc((size_t)NH * B_ * NV * 64 * 2); // 37.8 MB
  u16*  kh      = (u16*)alloc((size_t)NH * B_ * NV * 64 * 2); // 37.8 MB
  u16*  vh      = (u16*)alloc((size_t)NH * B_ * NV * 64 * 2); // 37.8 MB
  u16*  Obuf    = (u16*)alloc((size_t)MP * CDIM * 2);       // 31.6 MB
  float* tgt    = (float*)alloc((size_t)B_ * CDIM * 4);
  float* tb     = (float*)alloc((size_t)B_ * 384 * 4);      // dp1 tgt-term (incl dp1_b)
  u16*  xsh     = (u16*)alloc((size_t)MD * CDIM * 2);       // 25.2 MB (x search rows, hi)
  u16*  xsl     = (u16*)alloc((size_t)MD * CDIM * 2);       // 25.2 MB (lo)
  u16*  w1h     = (u16*)alloc((size_t)384 * CDIM * 2);
  u16*  w1l     = (u16*)alloc((size_t)384 * CDIM * 2);
  u16*  w2h     = (u16*)alloc((size_t)256 * 384 * 2);
  u16*  w2l     = (u16*)alloc((size_t)256 * 384 * 2);
  u16*  h1h     = (u16*)alloc((size_t)MD * 384 * 2);        // 12.6 MB
  u16*  h1l     = (u16*)alloc((size_t)MD * 384 * 2);        // 12.6 MB
  float* h2f    = (float*)alloc((size_t)MD * 256 * 4);      // 16.8 MB (gelu'd, padded)
  float* sdec   = (float*)alloc((size_t)MD * 4);

  // fused prep: x convert + search-row split; all weight converts/splits; tgt mean
  k_prep_x<<<dim3(MQ), dim3(192), 0, stream>>>(x, (ushort4*)xb, (ushort4*)xsh, (ushort4*)xsl);
  k_prep_w<<<dim3(PR3/256), dim3(256), 0, stream>>>(qkv_w, proj_w, dp1_w, dp2_w,
                                                    (ushort4*)qkv_wb, (ushort4*)proj_wb,
                                                    (ushort4*)w1h, (ushort4*)w1l,
                                                    (ushort4*)w2h, (ushort4*)w2l);
  k_tgt<<<dim3(B_), dim3(CDIM), 0, stream>>>(x, tgt);

  // qkv = x @ qkv_w.T + qkv_b  (bf16 out, scattered to head-major Q/K/V)
  k_gemm128<<<dim3(2304/128, (MQ + 127)/128), dim3(256), 0, stream>>>(xb, qkv_wb, qkv_b, qh, kh, vh,
                                                                      (float*)nullptr, MQ, 2304, CDIM, 0);
  // tb = tgt @ dp1_w[:,768:].T + dp1_b
  k_tb<<<dim3(B_), dim3(256), 0, stream>>>(tgt, dp1_w, dp1_b, tb);
  // dp1: h1 = gelu(Xs @ W1a.T + tb), split-fp32 via 3x bf16 MFMA, emits h1 hi/lo
  k_gemm128s<<<dim3(384/128, MD/128), dim3(256), 0, stream>>>(xsh, xsl, w1h, w1l,
                                                              nullptr, tb, h1h, h1l, nullptr,
                                                              MD, 384, CDIM, 384, 1, 0);
  // dp2: h2f = gelu(h1 @ W2.T + b2) (f32, N padded to 256)
  k_gemm128s<<<dim3(256/128, MD/128), dim3(256), 0, stream>>>(h1h, h1l, w2h, w2l,
                                                              dp2_b, nullptr, nullptr, nullptr, h2f,
                                                              MD, 256, 384, 192, 0, 1);
  k_decision<<<dim3(MD/4), dim3(256), 0, stream>>>(h2f, dp3_w, dp3_b, sdec);

  // attention (512 threads / 8 waves; q-tiles split across z)
  k_attn<<<dim3(B_, NH, 2), dim3(512), 0, stream>>>(qh, kh, vh, sdec, Obuf);

  // out = O @ proj_w.T + proj_b (fp32 out)
  k_gemm128<<<dim3(CDIM/128, (MP + 127)/128), dim3(256), 0, stream>>>(Obuf, proj_wb, proj_b,
                                                                      nullptr, nullptr, nullptr, out,
                                                                      MP, CDIM, CDIM, 1);
}